// Round 2
// baseline (727.799 us; speedup 1.0000x reference)
//
#include <hip/hip_runtime.h>
#include <hip/hip_bf16.h>
#include <cstdint>
#include <cstddef>

#define NEG_INF -10000.0f

constexpr int BSZ  = 128;
constexpr int SEQ  = 64;     // L
constexpr int DIM  = 512;    // D
constexpr int HEADS = 8;
constexpr int NLAYER = 2;
constexpr int NCOL = BSZ * (SEQ + 1);   // 8320
constexpr int NCOLP = 8448;             // padded to 33*256 for 256-wide tiles
constexpr int NROW = BSZ * SEQ;         // 8192
constexpr int NSTRIP = NCOLP / 64;      // 132
constexpr float CMAX = 40.0f;           // analytic upper bound (max logit < 28)

typedef __attribute__((ext_vector_type(8))) short bf16x8;   // 8 bf16 in 4 VGPRs
typedef __attribute__((ext_vector_type(4))) float f32x4;

// async global->LDS, 16B per lane, dest = ldsbase + lane*16
__device__ __forceinline__ void async_copy16(const void* g, void* l) {
    __builtin_amdgcn_global_load_lds(
        (const __attribute__((address_space(1))) void*)g,
        (__attribute__((address_space(3))) void*)l, 16, 0, 0);
}

__device__ __forceinline__ float b2f(uint16_t u) {
    return __builtin_bit_cast(float, (uint32_t)u << 16);
}
__device__ __forceinline__ uint16_t f2b(float f) {
    __hip_bfloat16 h = __float2bfloat16(f);
    return __builtin_bit_cast(uint16_t, h);
}

__device__ __forceinline__ float gelu_f(float v) {
    float u = 0.7978845608028654f * (v + 0.044715f * v * v * v);
    return 0.5f * v * (1.0f + tanhf(u));
}

// XCD-aware swizzle for the legacy 128-tile GEMM (64 row-blocks of 128 rows).
__device__ __forceinline__ void swizzle_rc(int id, int& ry, int& cx) {
    ry = (id & 7) * 8 + ((id >> 3) & 7);
    cx = id >> 6;
}

#define BAR() __builtin_amdgcn_s_barrier()
#define LGKM0() asm volatile("s_waitcnt lgkmcnt(0)" ::: "memory")
#define VMCNT(n) asm volatile("s_waitcnt vmcnt(" #n ")" ::: "memory")

// ---------------------------------------------------------------- gather + pos + LN (wave per row)
__global__ __launch_bounds__(256) void gather_posln_kernel(
    const int* __restrict__ ids, const float* __restrict__ table,
    const float* __restrict__ pop, const float* __restrict__ pos,
    __hip_bfloat16* __restrict__ sebf, float* __restrict__ debias,
    __hip_bfloat16* __restrict__ xb) {
    const int w = threadIdx.x >> 6, lane = threadIdx.x & 63;
    const int k = blockIdx.x * 4 + w;              // 0..8319
    const int b = k / 65, s = k - b * 65;
    const int id = ids[k];
    const float* src = table + (size_t)id * DIM + lane * 8;
    float4 u0 = *(const float4*)src;
    float4 u1 = *(const float4*)(src + 4);
    float v[8] = {u0.x, u0.y, u0.z, u0.w, u1.x, u1.y, u1.z, u1.w};
    bf16x8 se;
    #pragma unroll
    for (int j = 0; j < 8; j++) se[j] = (short)f2b(v[j]);
    *(bf16x8*)((uint16_t*)sebf + (size_t)k * DIM + lane * 8) = se;
    if (lane == 0) debias[k] = logf(pop[id]);
    if (s < 64) {
        const float* pp = pos + (size_t)s * DIM + lane * 8;
        float4 p0 = *(const float4*)pp;
        float4 p1 = *(const float4*)(pp + 4);
        float t[8] = {v[0] + p0.x, v[1] + p0.y, v[2] + p0.z, v[3] + p0.w,
                      v[4] + p1.x, v[5] + p1.y, v[6] + p1.z, v[7] + p1.w};
        float sum = 0.f, sq = 0.f;
        #pragma unroll
        for (int j = 0; j < 8; j++) { sum += t[j]; sq += t[j] * t[j]; }
        #pragma unroll
        for (int off = 32; off > 0; off >>= 1) {
            sum += __shfl_xor(sum, off, 64);
            sq  += __shfl_xor(sq,  off, 64);
        }
        const float mean = sum * (1.0f / 512.0f);
        const float var  = sq * (1.0f / 512.0f) - mean * mean;
        const float rs = rsqrtf(var + 1e-5f);
        bf16x8 o;
        #pragma unroll
        for (int j = 0; j < 8; j++) o[j] = (short)f2b((t[j] - mean) * rs);
        *(bf16x8*)((uint16_t*)xb + (size_t)(b * 64 + s) * DIM + lane * 8) = o;
    }
}

// ---------------------------------------------------------------- masks (padded to NCOLP)
__global__ __launch_bounds__(256) void mask_kernel(
    const int* __restrict__ ids, const float* __restrict__ log_mask,
    uint8_t* __restrict__ colmask, uint8_t* __restrict__ padcol) {
    const int bi = blockIdx.x >> 3, seg = blockIdx.x & 7;
    __shared__ int sid[65];
    if (threadIdx.x < 65) sid[threadIdx.x] = ids[bi * 65 + threadIdx.x];
    __syncthreads();
    const int kend = (seg + 1) * (NCOLP / 8);
    for (int k = seg * (NCOLP / 8) + threadIdx.x; k < kend; k += 256) {
        uint8_t cmv, pcv;
        if (k < NCOL) {
            const int id = ids[k];
            bool mem = false;
            #pragma unroll
            for (int j = 0; j < 65; j++) mem |= (sid[j] == id);
            const int i2 = k / 65, jj = k - i2 * 65;
            const bool pc = (jj < 64) && (log_mask[i2 * 64 + jj] == 0.0f);
            cmv = (mem || pc) ? 1 : 0;
            pcv = pc ? 1 : 0;
        } else { cmv = 1; pcv = 1; }   // padded columns always masked
        colmask[(size_t)bi * NCOLP + k] = cmv;
        if (bi == 0) padcol[k] = pcv;
    }
}

// ---------------------------------------------------------------- weight transpose+cast
__global__ __launch_bounds__(256) void transpose_bf16_kernel(
    const float* __restrict__ W, __hip_bfloat16* __restrict__ WT, int K, int N) {
    __shared__ float tile[32][33];
    const size_t loff = (size_t)blockIdx.z * K * N;
    const int nt = blockIdx.x * 32, kt = blockIdx.y * 32;
    const int c = threadIdx.x & 31, r = threadIdx.x >> 5;
    #pragma unroll
    for (int p = 0; p < 4; p++)
        tile[p * 8 + r][c] = W[loff + (size_t)(kt + p * 8 + r) * N + nt + c];
    __syncthreads();
    #pragma unroll
    for (int p = 0; p < 4; p++)
        WT[loff + (size_t)(nt + p * 8 + r) * K + kt + c] = __float2bfloat16(tile[c][p * 8 + r]);
}

// ---------------------------------------------------------------- residual + LN (wave per row, bf16)
__global__ __launch_bounds__(256) void resid_ln_kernel(
    __hip_bfloat16* __restrict__ xb, const __hip_bfloat16* __restrict__ y) {
    const int w = threadIdx.x >> 6, lane = threadIdx.x & 63;
    const int row = blockIdx.x * 4 + w;
    uint16_t* xp = (uint16_t*)xb + (size_t)row * DIM + lane * 8;
    const uint16_t* yp = (const uint16_t*)y + (size_t)row * DIM + lane * 8;
    bf16x8 xv = *(const bf16x8*)xp;
    bf16x8 yv = *(const bf16x8*)yp;
    float t[8];
    float sum = 0.f, sq = 0.f;
    #pragma unroll
    for (int j = 0; j < 8; j++) {
        t[j] = b2f((uint16_t)xv[j]) + b2f((uint16_t)yv[j]);
        sum += t[j]; sq += t[j] * t[j];
    }
    #pragma unroll
    for (int off = 32; off > 0; off >>= 1) {
        sum += __shfl_xor(sum, off, 64);
        sq  += __shfl_xor(sq,  off, 64);
    }
    const float mean = sum * (1.0f / 512.0f);
    const float var  = sq * (1.0f / 512.0f) - mean * mean;
    const float rs = rsqrtf(var + 1e-5f);
    bf16x8 o;
    #pragma unroll
    for (int j = 0; j < 8; j++) o[j] = (short)f2b((t[j] - mean) * rs);
    *(bf16x8*)xp = o;
}

// ---------------------------------------------------------------- legacy bf16 MFMA GEMM (B^T), BK=64
// Used for out-proj / ffn2 where N=512 doesn't fit 256-wide tiles well.
template<int TN, bool GELU>
__global__ __launch_bounds__(256) void gemm_bt_kernel(
    const __hip_bfloat16* __restrict__ A, const __hip_bfloat16* __restrict__ Bt,
    __hip_bfloat16* __restrict__ C, int N, int K) {
    __shared__ uint16_t As[2][128][32];
    __shared__ uint16_t Bs[2][TN][32];
    const int tid = threadIdx.x, w = tid >> 6, lane = tid & 63;
    const int quad = lane >> 4, l15 = lane & 15;
    constexpr int AI = (TN == 128) ? 4 : 2;
    const int wr = (TN == 128) ? (w >> 1) : w;
    const int wc = (TN == 128) ? (w & 1) : 0;
    const int rowbase = wr * (AI * 16);
    int ry, cx;
    swizzle_rc(blockIdx.x, ry, cx);
    const int row0 = ry * 128, col0 = cx * TN;
    const uint16_t* Ag = (const uint16_t*)A;
    const uint16_t* Bg = (const uint16_t*)Bt;
    const int sr = lane >> 2, sc = (lane & 3) * 8;
    f32x4 acc[AI][4];
    #pragma unroll
    for (int i = 0; i < AI; i++)
        #pragma unroll
        for (int j = 0; j < 4; j++) acc[i][j] = {0.f, 0.f, 0.f, 0.f};

    for (int k0 = 0; k0 < K; k0 += 64) {
        #pragma unroll
        for (int h = 0; h < 2; h++) {
            #pragma unroll
            for (int i = 0; i < 2; i++) {
                const int rb = w * 32 + i * 16;
                async_copy16(Ag + (size_t)(row0 + rb + sr) * K + k0 + h * 32 + sc, &As[h][rb][0]);
            }
            if (TN == 128) {
                #pragma unroll
                for (int i = 0; i < 2; i++) {
                    const int rb = w * 32 + i * 16;
                    async_copy16(Bg + (size_t)(col0 + rb + sr) * K + k0 + h * 32 + sc, &Bs[h][rb][0]);
                }
            } else {
                const int rb = w * 16;
                async_copy16(Bg + (size_t)(col0 + rb + sr) * K + k0 + h * 32 + sc, &Bs[h][rb][0]);
            }
        }
        __syncthreads();
        #pragma unroll
        for (int h = 0; h < 2; h++) {
            bf16x8 af[AI], bfr[4];
            #pragma unroll
            for (int i = 0; i < AI; i++)
                af[i] = *(const bf16x8*)&As[h][rowbase + i * 16 + l15][quad * 8];
            #pragma unroll
            for (int j = 0; j < 4; j++)
                bfr[j] = *(const bf16x8*)&Bs[h][wc * 64 + j * 16 + l15][quad * 8];
            #pragma unroll
            for (int i = 0; i < AI; i++)
                #pragma unroll
                for (int j = 0; j < 4; j++)
                    acc[i][j] = __builtin_amdgcn_mfma_f32_16x16x32_bf16(af[i], bfr[j], acc[i][j], 0, 0, 0);
        }
        __syncthreads();
    }
    #pragma unroll
    for (int i = 0; i < AI; i++) {
        #pragma unroll
        for (int r = 0; r < 4; r++) {
            const int row = row0 + rowbase + i * 16 + quad * 4 + r;
            #pragma unroll
            for (int j = 0; j < 4; j++) {
                const int col = col0 + wc * 64 + j * 16 + l15;
                float v = acc[i][j][r];
                if (GELU) v = gelu_f(v);
                C[(size_t)row * N + col] = __float2bfloat16(v);
            }
        }
    }
}

// ---------------------------------------------------------------- MFMA attention (per b,h)
__global__ __launch_bounds__(256) void attn_mfma_kernel(
    const __hip_bfloat16* __restrict__ qkv, const float* __restrict__ log_mask,
    __hip_bfloat16* __restrict__ obuf) {
    constexpr int QS = 72;    // Q/K/P LDS row stride (uint16)
    constexpr int VS32 = 36;  // V^T LDS row stride (uint32 pairs)
    __shared__ uint16_t Qs[64 * QS];
    __shared__ uint16_t Ks_[64 * QS];
    __shared__ uint16_t Ps[64 * QS];
    __shared__ uint32_t Vt32[64 * VS32];   // Vt32[d][sp] = (V[2sp][d], V[2sp+1][d])
    __shared__ float mask_s[64];
    const int b = blockIdx.x >> 3, h = blockIdx.x & 7;
    const int tid = threadIdx.x, w = tid >> 6, lane = tid & 63;
    const int quad = lane >> 4, l15 = lane & 15;
    const uint16_t* qg = (const uint16_t*)qkv;

    if (tid < 64) mask_s[tid] = log_mask[b * 64 + tid];
    // stage Q,K row-major
    #pragma unroll
    for (int it = 0; it < 2; it++) {
        const int idx = it * 256 + tid;          // 0..511
        const int s = idx >> 3, c = (idx & 7) * 8;
        const size_t gbase = (size_t)(b * 64 + s) * 1536 + h * 64 + c;
        *(bf16x8*)&Qs[s * QS + c]  = *(const bf16x8*)&qg[gbase];
        *(bf16x8*)&Ks_[s * QS + c] = *(const bf16x8*)&qg[gbase + 512];
    }
    // stage V transposed, two rows packed per 32-bit word
    {
        const int sp = tid >> 3;                 // 0..31
        const int c = (tid & 7) * 8;
        const size_t gbase = (size_t)(b * 64 + sp * 2) * 1536 + 1024 + h * 64 + c;
        bf16x8 v0 = *(const bf16x8*)&qg[gbase];
        bf16x8 v1 = *(const bf16x8*)&qg[gbase + 1536];
        #pragma unroll
        for (int jj = 0; jj < 8; jj++)
            Vt32[(c + jj) * VS32 + sp] =
                (uint32_t)(uint16_t)v0[jj] | ((uint32_t)(uint16_t)v1[jj] << 16);
    }
    __syncthreads();

    // ---- S = Q K^T for rows w*16..w*16+15
    f32x4 sacc[4];
    #pragma unroll
    for (int j = 0; j < 4; j++) sacc[j] = {0.f, 0.f, 0.f, 0.f};
    #pragma unroll
    for (int k0 = 0; k0 < 2; k0++) {
        bf16x8 aq = *(const bf16x8*)&Qs[(w * 16 + l15) * QS + k0 * 32 + quad * 8];
        #pragma unroll
        for (int j = 0; j < 4; j++) {
            bf16x8 bk = *(const bf16x8*)&Ks_[(j * 16 + l15) * QS + k0 * 32 + quad * 8];
            sacc[j] = __builtin_amdgcn_mfma_f32_16x16x32_bf16(aq, bk, sacc[j], 0, 0, 0);
        }
    }
    // ---- softmax per row; P -> LDS bf16
    #pragma unroll
    for (int r = 0; r < 4; r++) {
        const int q = w * 16 + quad * 4 + r;
        float vals[4];
        float vmax = -3.0e38f;
        #pragma unroll
        for (int j = 0; j < 4; j++) {
            const int col = j * 16 + l15;
            const bool ok = (col <= q) && (mask_s[col] != 0.0f);
            float v = sacc[j][r] * 0.125f + (ok ? 0.0f : NEG_INF);
            vals[j] = v;
            vmax = fmaxf(vmax, v);
        }
        #pragma unroll
        for (int off = 1; off < 16; off <<= 1) vmax = fmaxf(vmax, __shfl_xor(vmax, off, 64));
        float e[4], s = 0.f;
        #pragma unroll
        for (int j = 0; j < 4; j++) { e[j] = __expf(vals[j] - vmax); s += e[j]; }
        #pragma unroll
        for (int off = 1; off < 16; off <<= 1) s += __shfl_xor(s, off, 64);
        const float inv = 1.0f / s;
        #pragma unroll
        for (int j = 0; j < 4; j++)
            Ps[q * QS + j * 16 + l15] = f2b(e[j] * inv);
    }
    __syncthreads();

    // ---- O = P V : B-frags contiguous b128 from Vt32
    f32x4 oacc[4];
    #pragma unroll
    for (int j = 0; j < 4; j++) oacc[j] = {0.f, 0.f, 0.f, 0.f};
    #pragma unroll
    for (int k0 = 0; k0 < 2; k0++) {
        bf16x8 ap = *(const bf16x8*)&Ps[(w * 16 + l15) * QS + k0 * 32 + quad * 8];
        #pragma unroll
        for (int j = 0; j < 4; j++) {
            bf16x8 bv = *(const bf16x8*)&Vt32[(j * 16 + l15) * VS32 + k0 * 16 + quad * 4];
            oacc[j] = __builtin_amdgcn_mfma_f32_16x16x32_bf16(ap, bv, oacc[j], 0, 0, 0);
        }
    }
    #pragma unroll
    for (int r = 0; r < 4; r++) {
        const int q = w * 16 + quad * 4 + r;
        #pragma unroll
        for (int j = 0; j < 4; j++) {
            const int d = j * 16 + l15;
            obuf[(size_t)(b * 64 + q) * 512 + h * 64 + d] = __float2bfloat16(oacc[j][r]);
        }
    }
}

// ---------------------------------------------------------------- 256x256 8-wave 8-phase GEMM (B^T)
// T2 (XOR-8 LDS swizzle, both-sides w/ linear global_load_lds dest) +
// T3/T4 (8-phase, counted vmcnt(4) gates at P4/P8) + T5 (setprio around MFMA).
// Requires M == 8192 (32 row-tiles), K % 128 == 0, grid = 32 * (Ncols/256), grid%8==0.
// XCD swizzle: each XCD owns a 4-row-tile band (1 MB of A, L2-resident) and walks
// columns; per-XCD concurrent set = 1 MB A + ~2 MB B < 4 MB L2.
// EPI: 0 = plain bf16 store, 1 = gelu store, 2 = fused logits softmax partials.
template<int EPI>
__global__ __launch_bounds__(512) void gemm256_kernel(
    const __hip_bfloat16* __restrict__ A, const __hip_bfloat16* __restrict__ Bt,
    __hip_bfloat16* __restrict__ C, int N, int K,
    const float* __restrict__ debias, const uint8_t* __restrict__ colmask,
    float* __restrict__ partials) {
    __shared__ uint16_t SA[2][2][128 * 64];   // [ktile-slot][half][row*64 + swz-col]
    __shared__ uint16_t SB[2][2][128 * 64];
    __shared__ float dc_s[256];
    __shared__ uint8_t cm_s[4][256];

    const int tid = threadIdx.x;
    const int w = tid >> 6, lane = tid & 63;
    const int quad = lane >> 4, l15 = lane & 15;
    const int wr = w >> 2, wc = w & 3;        // 2(M) x 4(N) wave grid, wave = 128x64

    // row-band XCD swizzle: xcd = bid&7 owns ry in [xcd*4, xcd*4+4), cx walks slow
    const int kb = blockIdx.x >> 3;
    const int ry = (blockIdx.x & 7) * 4 + (kb & 3), cx = kb >> 2;
    const int row0 = ry * 256, col0 = cx * 256;

    const uint16_t* Ag = (const uint16_t*)A;
    const uint16_t* Bg = (const uint16_t*)Bt;

    if (EPI == 2) {
        if (tid < 256) dc_s[tid] = debias[col0 + tid] + CMAX;
        #pragma unroll
        for (int j = 0; j < 2; j++) {
            const int e = j * 512 + tid;
            cm_s[e >> 8][e & 255] =
                colmask[(size_t)((row0 >> 6) + (e >> 8)) * NCOLP + col0 + (e & 255)];
        }
    }

    // per-lane swizzled staging source pointers; LDS dest stays linear (rule #21)
    const int tb0 = w << 6, tb1 = 512 + (w << 6);
    const uint16_t* gA[2][2];
    const uint16_t* gB[2][2];
    #pragma unroll
    for (int j = 0; j < 2; j++) {
        const int t = j * 512 + (w << 6) + lane;
        const int r = t >> 3;
        const int s = (t & 7) ^ (r & 7);      // inverse-swizzled global col-block
        #pragma unroll
        for (int h = 0; h < 2; h++) {
            gA[h][j] = Ag + (size_t)(row0 + h * 128 + r) * K + s * 8;
            gB[h][j] = Bg + (size_t)(col0 + h * 128 + r) * K + s * 8;
        }
    }

    #define STAGE_A(tile, half, k0) do { \
        async_copy16(gA[half][0] + (k0), &SA[tile][half][tb0 * 8]); \
        async_copy16(gA[half][1] + (k0), &SA[tile][half][tb1 * 8]); } while (0)
    #define STAGE_B(tile, half, k0) do { \
        async_copy16(gB[half][0] + (k0), &SB[tile][half][tb0 * 8]); \
        async_copy16(gB[half][1] + (k0), &SB[tile][half][tb1 * 8]); } while (0)

    // swizzled reads: slot' = slot ^ (row&7)  -> 2-way max per 16-lane phase (free)
    auto fragA = [&](int tile, int m, int kk) -> bf16x8 {
        return *(const bf16x8*)&SA[tile][wr]
            [((m * 16 + l15) << 6) + ((((kk << 2) + quad) ^ (l15 & 7)) << 3)];
    };
    auto fragB = [&](int tile, int n, int kk) -> bf16x8 {
        return *(const bf16x8*)&SB[tile][wc >> 1]
            [(((wc & 1) * 64 + n * 16 + l15) << 6) + ((((kk << 2) + quad) ^ (l15 & 7)) << 3)];
    };

    f32x4 acc[8][4];
    #pragma unroll
    for (int m = 0; m < 8; m++)
        #pragma unroll
        for (int n = 0; n < 4; n++) acc[m][n] = {0.f, 0.f, 0.f, 0.f};

    // prologue: tile0 (all 4 halves) + tile1 A-h0/B-h0. Tile1 h1's come in P1/P2.
    STAGE_A(0, 0, 0); STAGE_A(0, 1, 0);
    STAGE_B(0, 0, 0); STAGE_B(0, 1, 0);
    STAGE_A(1, 0, 64); STAGE_B(1, 0, 64);
    VMCNT(4);          // tile0 fully landed; tile1 h0's may fly (gated at P4)
    BAR();

    const int niters = K >> 7;   // 2 K-tiles (BK=64) per iteration
    bf16x8 af[4][2], bA[2][2], bB[2][2];
    for (int it = 0; it < niters; ++it) {
        const bool st = (it + 1 < niters);
        const int kc = it << 7;
        const int kn = kc + 128;

        // ---- P1: tile0 m0-3 x n0-1; stage tile(2it+1) A-h1
        #pragma unroll
        for (int m = 0; m < 4; m++) { af[m][0] = fragA(0, m, 0); af[m][1] = fragA(0, m, 1); }
        #pragma unroll
        for (int n = 0; n < 2; n++) { bA[n][0] = fragB(0, n, 0); bA[n][1] = fragB(0, n, 1); }
        STAGE_A(1, 1, kc + 64);
        BAR(); LGKM0();
        __builtin_amdgcn_s_setprio(1);
        #pragma unroll
        for (int m = 0; m < 4; m++)
            #pragma unroll
            for (int n = 0; n < 2; n++) {
                acc[m][n] = __builtin_amdgcn_mfma_f32_16x16x32_bf16(af[m][0], bA[n][0], acc[m][n], 0, 0, 0);
                acc[m][n] = __builtin_amdgcn_mfma_f32_16x16x32_bf16(af[m][1], bA[n][1], acc[m][n], 0, 0, 0);
            }
        __builtin_amdgcn_s_setprio(0);
        BAR();

        // ---- P2: tile0 m0-3 x n2-3; stage tile(2it+1) B-h1
        #pragma unroll
        for (int n = 0; n < 2; n++) { bB[n][0] = fragB(0, n + 2, 0); bB[n][1] = fragB(0, n + 2, 1); }
        STAGE_B(1, 1, kc + 64);
        BAR(); LGKM0();
        __builtin_amdgcn_s_setprio(1);
        #pragma unroll
        for (int m = 0; m < 4; m++)
            #pragma unroll
            for (int n = 0; n < 2; n++) {
                acc[m][n + 2] = __builtin_amdgcn_mfma_f32_16x16x32_bf16(af[m][0], bB[n][0], acc[m][n + 2], 0, 0, 0);
                acc[m][n + 2] = __builtin_amdgcn_mfma_f32_16x16x32_bf16(af[m][1], bB[n][1], acc[m][n + 2], 0, 0, 0);
            }
        __builtin_amdgcn_s_setprio(0);
        BAR();

        // ---- P3: tile0 m4-7 x n2-3; stage tile(2it+2) B-h0
        #pragma unroll
        for (int m = 0; m < 4; m++) { af[m][0] = fragA(0, m + 4, 0); af[m][1] = fragA(0, m + 4, 1); }
        if (st) STAGE_B(0, 0, kn);
        BAR(); LGKM0();
        __builtin_amdgcn_s_setprio(1);
        #pragma unroll
        for (int m = 0; m < 4; m++)
            #pragma unroll
            for (int n = 0; n < 2; n++) {
                acc[m + 4][n + 2] = __builtin_amdgcn_mfma_f32_16x16x32_bf16(af[m][0], bB[n][0], acc[m + 4][n + 2], 0, 0, 0);
                acc[m + 4][n + 2] = __builtin_amdgcn_mfma_f32_16x16x32_bf16(af[m][1], bB[n][1], acc[m + 4][n + 2], 0, 0, 0);
            }
        __builtin_amdgcn_s_setprio(0);
        BAR();

        // ---- P4: tile0 m4-7 x n0-1 (regs only); stage tile(2it+2) A-h0; vmcnt gate
        if (st) STAGE_A(0, 0, kn);
        __builtin_amdgcn_s_setprio(1);
        #pragma unroll
        for (int m = 0; m < 4; m++)
            #pragma unroll
            for (int n = 0; n < 2; n++) {
                acc[m + 4][n] = __builtin_amdgcn_mfma_f32_16x16x32_bf16(af[m][0], bA[n][0], acc[m + 4][n], 0, 0, 0);
                acc[m + 4][n] = __builtin_amdgcn_mfma_f32_16x16x32_bf16(af[m][1], bA[n][1], acc[m + 4][n], 0, 0, 0);
            }
        __builtin_amdgcn_s_setprio(0);
        if (st) { VMCNT(4); } else { VMCNT(0); }   // tile1 halves (prevP7,prevP8,P1,P2) landed
        BAR();

        // ---- P5: tile1 m0-3 x n0-1; stage tile(2it+2) A-h1
        #pragma unroll
        for (int m = 0; m < 4; m++) { af[m][0] = fragA(1, m, 0); af[m][1] = fragA(1, m, 1); }
        #pragma unroll
        for (int n = 0; n < 2; n++) { bA[n][0] = fragB(1, n, 0); bA[n][1] = fragB(1, n, 1); }
        if (st) STAGE_A(0, 1, kn);
        BAR(); LGKM0();
        __builtin_amdgcn_s_setprio(1);
        #pragma unroll
        for (int m = 0; m < 4; m++)
            #pragma unroll
            for (int n = 0; n < 2; n++) {
                acc[m][n] = __builtin_amdgcn_mfma_f32_16x16x32_bf16(af[m][0], bA[n][0], acc[m][n], 0, 0, 0);
                acc[m][n] = __builtin_amdgcn_mfma_f32_16x16x32_bf16(af[m][1], bA[n][1], acc[m][n], 0, 0, 0);
            }
        __builtin_amdgcn_s_setprio(0);
        BAR();

        // ---- P6: tile1 m0-3 x n2-3; stage tile(2it+2) B-h1
        #pragma unroll
        for (int n = 0; n < 2; n++) { bB[n][0] = fragB(1, n + 2, 0); bB[n][1] = fragB(1, n + 2, 1); }
        if (st) STAGE_B(0, 1, kn);
        BAR(); LGKM0();
        __builtin_amdgcn_s_setprio(1);
        #pragma unroll
        for (int m = 0; m < 4; m++)
            #pragma unroll
            for (int n = 0; n < 2; n++) {
                acc[m][n + 2] = __builtin_amdgcn_mfma_f32_16x16x32_bf16(af[m][0], bB[n][0], acc[m][n + 2], 0, 0, 0);
                acc[m][n + 2] = __builtin_amdgcn_mfma_f32_16x16x32_bf16(af[m][1], bB[n][1], acc[m][n + 2], 0, 0, 0);
            }
        __builtin_amdgcn_s_setprio(0);
        BAR();

        // ---- P7: tile1 m4-7 x n2-3; stage tile(2it+3) B-h0
        #pragma unroll
        for (int m = 0; m < 4; m++) { af[m][0] = fragA(1, m + 4, 0); af[m][1] = fragA(1, m + 4, 1); }
        if (st) STAGE_B(1, 0, kn + 64);
        BAR(); LGKM0();
        __builtin_amdgcn_s_setprio(1);
        #pragma unroll
        for (int m = 0; m < 4; m++)
            #pragma unroll
            for (int n = 0; n < 2; n++) {
                acc[m + 4][n + 2] = __builtin_amdgcn_mfma_f32_16x16x32_bf16(af[m][0], bB[n][0], acc[m + 4][n + 2], 0, 0, 0);
                acc[m + 4][n + 2] = __builtin_amdgcn_mfma_f32_16x16x32_bf16(af[m][1], bB[n][1], acc[m + 4][n + 2], 0, 0, 0);
            }
        __builtin_amdgcn_s_setprio(0);
        BAR();

        // ---- P8: tile1 m4-7 x n0-1 (regs only); stage tile(2it+3) A-h0; vmcnt gate
        if (st) STAGE_A(1, 0, kn + 64);
        __builtin_amdgcn_s_setprio(1);
        #pragma unroll
        for (int m = 0; m < 4; m++)
            #pragma unroll
            for (int n = 0; n < 2; n++) {
                acc[m + 4][n] = __builtin_amdgcn_mfma_f32_16x16x32_bf16(af[m][0], bA[n][0], acc[m + 4][n], 0, 0, 0);
                acc[m + 4][n] = __builtin_amdgcn_mfma_f32_16x16x32_bf16(af[m][1], bA[n][1], acc[m + 4][n], 0, 0, 0);
            }
        __builtin_amdgcn_s_setprio(0);
        if (st) { VMCNT(4); BAR(); }               // next tile0 (P3,P4,P5,P6) landed
    }

    // ---------------- epilogue
    if (EPI == 2) {
        const int strip = cx * 4 + wc;
        #pragma unroll
        for (int m = 0; m < 8; m++) {
            #pragma unroll
            for (int r = 0; r < 4; r++) {
                const int lrow = wr * 128 + m * 16 + quad * 4 + r;
                const int row = row0 + lrow;
                float s = 0.f;
                #pragma unroll
                for (int n = 0; n < 4; n++) {
                    const int lcol = wc * 64 + n * 16 + l15;
                    float t = acc[m][n][r] - dc_s[lcol];          // = v - deb - CMAX
                    t = (cm_s[lrow >> 6][lcol] != 0) ? -1.0e30f : t;
                    s += __expf(t);
                }
                #pragma unroll
                for (int off = 1; off < 16; off <<= 1) s += __shfl_xor(s, off, 64);
                if (l15 == 0) partials[(size_t)row * NSTRIP + strip] = s;
            }
        }
    } else {
        #pragma unroll
        for (int m = 0; m < 8; m++) {
            #pragma unroll
            for (int r = 0; r < 4; r++) {
                const int row = row0 + wr * 128 + m * 16 + quad * 4 + r;
                #pragma unroll
                for (int n = 0; n < 4; n++) {
                    const int col = col0 + wc * 64 + n * 16 + l15;
                    float v = acc[m][n][r];
                    if (EPI == 1) v = gelu_f(v);
                    C[(size_t)row * N + col] = __float2bfloat16(v);
                }
            }
        }
    }
    #undef STAGE_A
    #undef STAGE_B
}

// ---------------------------------------------------------------- label logits (wave per row)
__global__ __launch_bounds__(256) void label_kernel(
    const __hip_bfloat16* __restrict__ xb, const __hip_bfloat16* __restrict__ sebf,
    const float* __restrict__ debias, const uint8_t* __restrict__ padcol,
    float* __restrict__ lab) {
    const int w = threadIdx.x >> 6, lane = threadIdx.x & 63;
    const int row = blockIdx.x * 4 + w;            // 0..8191
    const int b = row >> 6, s0 = row & 63;
    const int k = b * 65 + s0 + 1;
    const uint16_t* xp = (const uint16_t*)xb + (size_t)row * DIM + lane * 8;
    const uint16_t* sp = (const uint16_t*)sebf + (size_t)k * DIM + lane * 8;
    bf16x8 xv = *(const bf16x8*)xp;
    bf16x8 sv = *(const bf16x8*)sp;
    float a = 0.f;
    #pragma unroll
    for (int j = 0; j < 8; j++) a += b2f((uint16_t)xv[j]) * b2f((uint16_t)sv[j]);
    #pragma unroll
    for (int off = 32; off > 0; off >>= 1) a += __shfl_xor(a, off, 64);
    if (lane == 0)
        lab[row] = padcol[k] ? NEG_INF : (a - debias[k]);
}

// ---------------------------------------------------------------- combine + reduce
__global__ __launch_bounds__(256) void combine_kernel(
    const float* __restrict__ partials, const float* __restrict__ label_logit,
    const float* __restrict__ log_mask, float* __restrict__ bsums) {
    const int row = blockIdx.x * 256 + threadIdx.x;
    const float lab = label_logit[row];
    // label column is colmask'd in the GEMM; re-add its exp term here
    float Ls = __expf(lab - CMAX);
    const float4* pr = (const float4*)(partials + (size_t)row * NSTRIP);
    for (int t = 0; t < NSTRIP / 4; t++) {
        float4 v = pr[t];
        Ls += v.x + v.y + v.z + v.w;
    }
    const float lse = CMAX + logf(Ls);
    const float valid = (log_mask[row] != 0.0f) ? 1.0f : 0.0f;
    float a = (lse - lab) * valid;
    float c = valid;
    __shared__ float sa[4], sc_[4];
    #pragma unroll
    for (int off = 32; off > 0; off >>= 1) {
        a += __shfl_down(a, off, 64);
        c += __shfl_down(c, off, 64);
    }
    const int lane = threadIdx.x & 63, w = threadIdx.x >> 6;
    if (lane == 0) { sa[w] = a; sc_[w] = c; }
    __syncthreads();
    if (threadIdx.x == 0) {
        bsums[blockIdx.x * 2 + 0] = sa[0] + sa[1] + sa[2] + sa[3];
        bsums[blockIdx.x * 2 + 1] = sc_[0] + sc_[1] + sc_[2] + sc_[3];
    }
}

__global__ __launch_bounds__(64) void finalize_kernel(
    const float* __restrict__ bsums, float* __restrict__ out) {
    const int t = threadIdx.x;
    float a = 0.f, c = 0.f;
    if (t < 32) { a = bsums[2 * t]; c = bsums[2 * t + 1]; }
    #pragma unroll
    for (int off = 32; off > 0; off >>= 1) {
        a += __shfl_down(a, off, 64);
        c += __shfl_down(c, off, 64);
    }
    if (t == 0) out[0] = a / c;
}

// ---------------------------------------------------------------- launch
extern "C" void kernel_launch(void* const* d_in, const int* in_sizes, int n_in,
                              void* d_out, int out_size, void* d_ws, size_t ws_size,
                              hipStream_t stream) {
    const int*   ids    = (const int*)d_in[0];
    const float* lm     = (const float*)d_in[1];
    const float* emb    = (const float*)d_in[2];
    const float* pos    = (const float*)d_in[3];
    const float* qkv_w  = (const float*)d_in[4];
    const float* out_w  = (const float*)d_in[5];
    const float* ffn1_w = (const float*)d_in[6];
    const float* ffn2_w = (const float*)d_in[7];
    const float* pop    = (const float*)d_in[8];
    float* out = (float*)d_out;

    char* p = (char*)d_ws;
    auto alloc = [&](size_t bytes) {
        char* r = p;
        p += (bytes + 255) & ~(size_t)255;
        return r;
    };
    typedef __hip_bfloat16 bf16;
    bf16*    sebf     = (bf16*)alloc((size_t)NCOLP * DIM * 2);       // 8.65 MB (padded)
    float*   debias   = (float*)alloc((size_t)NCOLP * 4);
    uint8_t* padcol   = (uint8_t*)alloc(NCOLP);
    uint8_t* colmask  = (uint8_t*)alloc((size_t)BSZ * NCOLP);        // 1.08 MB (padded)
    bf16*    xb       = (bf16*)alloc((size_t)NROW * DIM * 2);        // 8.4 MB (residual)
    bf16*    big      = (bf16*)alloc((size_t)NROW * 2048 * 2);       // 33.6 MB (qkv / h)
    bf16*    tmp1     = (bf16*)alloc((size_t)NROW * DIM * 2);        // attn out
    bf16*    tmp2     = (bf16*)alloc((size_t)NROW * DIM * 2);        // proj / f2
    float*   partials = (float*)alloc((size_t)NROW * NSTRIP * 4);    // 4.3 MB
    float*   lab      = (float*)alloc((size_t)NROW * 4);
    float*   bsums    = (float*)alloc(64 * 4);
    bf16*    qkvT     = (bf16*)alloc((size_t)NLAYER * 1536 * 512 * 2);
    bf16*    outT     = (bf16*)alloc((size_t)NLAYER * 512 * 512 * 2);
    bf16*    f1T      = (bf16*)alloc((size_t)NLAYER * 2048 * 512 * 2);
    bf16*    f2T      = (bf16*)alloc((size_t)NLAYER * 512 * 2048 * 2);

    transpose_bf16_kernel<<<dim3(1536 / 32, 512 / 32, NLAYER), 256, 0, stream>>>(
        qkv_w, qkvT, 512, 1536);
    transpose_bf16_kernel<<<dim3(512 / 32, 512 / 32, NLAYER), 256, 0, stream>>>(
        out_w, outT, 512, 512);
    transpose_bf16_kernel<<<dim3(2048 / 32, 512 / 32, NLAYER), 256, 0, stream>>>(
        ffn1_w, f1T, 512, 2048);
    transpose_bf16_kernel<<<dim3(512 / 32, 2048 / 32, NLAYER), 256, 0, stream>>>(
        ffn2_w, f2T, 2048, 512);

    gather_posln_kernel<<<NCOL / 4, 256, 0, stream>>>(ids, emb, pop, pos, sebf, debias, xb);
    mask_kernel<<<BSZ * 8, 256, 0, stream>>>(ids, lm, colmask, padcol);

    for (int l = 0; l < NLAYER; l++) {
        gemm256_kernel<0><<<32 * (1536 / 256), 512, 0, stream>>>(
            xb, qkvT + (size_t)l * 1536 * 512, big, 1536, 512, nullptr, nullptr, nullptr);
        attn_mfma_kernel<<<BSZ * HEADS, 256, 0, stream>>>(big, lm, tmp1);
        gemm_bt_kernel<64, false><<<(512 / 64) * 64, 256, 0, stream>>>(
            tmp1, outT + (size_t)l * 512 * 512, tmp2, 512, 512);
        resid_ln_kernel<<<NROW / 4, 256, 0, stream>>>(xb, tmp2);
        gemm256_kernel<1><<<32 * (2048 / 256), 512, 0, stream>>>(
            xb, f1T + (size_t)l * 2048 * 512, big, 2048, 512, nullptr, nullptr, nullptr);
        gemm_bt_kernel<64, false><<<(512 / 64) * 64, 256, 0, stream>>>(
            big, f2T + (size_t)l * 512 * 2048, tmp2, 512, 2048);
        resid_ln_kernel<<<NROW / 4, 256, 0, stream>>>(xb, tmp2);
    }

    label_kernel<<<NROW / 4, 256, 0, stream>>>(xb, sebf, debias, padcol, lab);
    gemm256_kernel<2><<<32 * (NCOLP / 256), 512, 0, stream>>>(
        xb, sebf, nullptr, NCOLP, 512, debias, colmask, partials);
    combine_kernel<<<NROW / 256, 256, 0, stream>>>(partials, lab, lm, bsums);
    finalize_kernel<<<1, 64, 0, stream>>>(bsums, out);
}

// Round 3
// 671.927 us; speedup vs baseline: 1.0832x; 1.0832x over previous
//
#include <hip/hip_runtime.h>
#include <hip/hip_bf16.h>
#include <cstdint>
#include <cstddef>

#define NEG_INF -10000.0f

constexpr int BSZ  = 128;
constexpr int SEQ  = 64;     // L
constexpr int DIM  = 512;    // D
constexpr int HEADS = 8;
constexpr int NLAYER = 2;
constexpr int NCOL = BSZ * (SEQ + 1);   // 8320
constexpr int NCOLP = 8448;             // padded to 33*256 for 256-wide tiles
constexpr int NROW = BSZ * SEQ;         // 8192
constexpr int NSTRIP = NCOLP / 64;      // 132
constexpr float CMAX = 40.0f;           // analytic upper bound (max logit < 28)

typedef __attribute__((ext_vector_type(8))) short bf16x8;   // 8 bf16 in 4 VGPRs
typedef __attribute__((ext_vector_type(4))) float f32x4;

// async global->LDS, 16B per lane, dest = ldsbase + lane*16
__device__ __forceinline__ void async_copy16(const void* g, void* l) {
    __builtin_amdgcn_global_load_lds(
        (const __attribute__((address_space(1))) void*)g,
        (__attribute__((address_space(3))) void*)l, 16, 0, 0);
}

__device__ __forceinline__ float b2f(uint16_t u) {
    return __builtin_bit_cast(float, (uint32_t)u << 16);
}
__device__ __forceinline__ uint16_t f2b(float f) {
    __hip_bfloat16 h = __float2bfloat16(f);
    return __builtin_bit_cast(uint16_t, h);
}

__device__ __forceinline__ float gelu_f(float v) {
    float u = 0.7978845608028654f * (v + 0.044715f * v * v * v);
    return 0.5f * v * (1.0f + tanhf(u));
}

// XCD-aware swizzle for the 128-tile GEMM (64 row-blocks of 128 rows).
__device__ __forceinline__ void swizzle_rc(int id, int& ry, int& cx) {
    ry = (id & 7) * 8 + ((id >> 3) & 7);
    cx = id >> 6;
}

#define BAR() __builtin_amdgcn_s_barrier()
#define LGKM0() asm volatile("s_waitcnt lgkmcnt(0)" ::: "memory")
#define VMCNT(n) asm volatile("s_waitcnt vmcnt(" #n ")" ::: "memory")

// ---------------------------------------------------------------- gather + pos + LN (wave per row)
__global__ __launch_bounds__(256) void gather_posln_kernel(
    const int* __restrict__ ids, const float* __restrict__ table,
    const float* __restrict__ pop, const float* __restrict__ pos,
    __hip_bfloat16* __restrict__ sebf, float* __restrict__ debias,
    __hip_bfloat16* __restrict__ xb) {
    const int w = threadIdx.x >> 6, lane = threadIdx.x & 63;
    const int k = blockIdx.x * 4 + w;              // 0..8319
    const int b = k / 65, s = k - b * 65;
    const int id = ids[k];
    const float* src = table + (size_t)id * DIM + lane * 8;
    float4 u0 = *(const float4*)src;
    float4 u1 = *(const float4*)(src + 4);
    float v[8] = {u0.x, u0.y, u0.z, u0.w, u1.x, u1.y, u1.z, u1.w};
    bf16x8 se;
    #pragma unroll
    for (int j = 0; j < 8; j++) se[j] = (short)f2b(v[j]);
    *(bf16x8*)((uint16_t*)sebf + (size_t)k * DIM + lane * 8) = se;
    if (lane == 0) debias[k] = logf(pop[id]);
    if (s < 64) {
        const float* pp = pos + (size_t)s * DIM + lane * 8;
        float4 p0 = *(const float4*)pp;
        float4 p1 = *(const float4*)(pp + 4);
        float t[8] = {v[0] + p0.x, v[1] + p0.y, v[2] + p0.z, v[3] + p0.w,
                      v[4] + p1.x, v[5] + p1.y, v[6] + p1.z, v[7] + p1.w};
        float sum = 0.f, sq = 0.f;
        #pragma unroll
        for (int j = 0; j < 8; j++) { sum += t[j]; sq += t[j] * t[j]; }
        #pragma unroll
        for (int off = 32; off > 0; off >>= 1) {
            sum += __shfl_xor(sum, off, 64);
            sq  += __shfl_xor(sq,  off, 64);
        }
        const float mean = sum * (1.0f / 512.0f);
        const float var  = sq * (1.0f / 512.0f) - mean * mean;
        const float rs = rsqrtf(var + 1e-5f);
        bf16x8 o;
        #pragma unroll
        for (int j = 0; j < 8; j++) o[j] = (short)f2b((t[j] - mean) * rs);
        *(bf16x8*)((uint16_t*)xb + (size_t)(b * 64 + s) * DIM + lane * 8) = o;
    }
}

// ---------------------------------------------------------------- masks (padded to NCOLP)
__global__ __launch_bounds__(256) void mask_kernel(
    const int* __restrict__ ids, const float* __restrict__ log_mask,
    uint8_t* __restrict__ colmask, uint8_t* __restrict__ padcol) {
    const int bi = blockIdx.x >> 3, seg = blockIdx.x & 7;
    __shared__ int sid[65];
    if (threadIdx.x < 65) sid[threadIdx.x] = ids[bi * 65 + threadIdx.x];
    __syncthreads();
    const int kend = (seg + 1) * (NCOLP / 8);
    for (int k = seg * (NCOLP / 8) + threadIdx.x; k < kend; k += 256) {
        uint8_t cmv, pcv;
        if (k < NCOL) {
            const int id = ids[k];
            bool mem = false;
            #pragma unroll
            for (int j = 0; j < 65; j++) mem |= (sid[j] == id);
            const int i2 = k / 65, jj = k - i2 * 65;
            const bool pc = (jj < 64) && (log_mask[i2 * 64 + jj] == 0.0f);
            cmv = (mem || pc) ? 1 : 0;
            pcv = pc ? 1 : 0;
        } else { cmv = 1; pcv = 1; }   // padded columns always masked
        colmask[(size_t)bi * NCOLP + k] = cmv;
        if (bi == 0) padcol[k] = pcv;
    }
}

// ---------------------------------------------------------------- weight transpose+cast
__global__ __launch_bounds__(256) void transpose_bf16_kernel(
    const float* __restrict__ W, __hip_bfloat16* __restrict__ WT, int K, int N) {
    __shared__ float tile[32][33];
    const size_t loff = (size_t)blockIdx.z * K * N;
    const int nt = blockIdx.x * 32, kt = blockIdx.y * 32;
    const int c = threadIdx.x & 31, r = threadIdx.x >> 5;
    #pragma unroll
    for (int p = 0; p < 4; p++)
        tile[p * 8 + r][c] = W[loff + (size_t)(kt + p * 8 + r) * N + nt + c];
    __syncthreads();
    #pragma unroll
    for (int p = 0; p < 4; p++)
        WT[loff + (size_t)(nt + p * 8 + r) * K + kt + c] = __float2bfloat16(tile[c][p * 8 + r]);
}

// ---------------------------------------------------------------- residual + LN (wave per row, bf16)
__global__ __launch_bounds__(256) void resid_ln_kernel(
    __hip_bfloat16* __restrict__ xb, const __hip_bfloat16* __restrict__ y) {
    const int w = threadIdx.x >> 6, lane = threadIdx.x & 63;
    const int row = blockIdx.x * 4 + w;
    uint16_t* xp = (uint16_t*)xb + (size_t)row * DIM + lane * 8;
    const uint16_t* yp = (const uint16_t*)y + (size_t)row * DIM + lane * 8;
    bf16x8 xv = *(const bf16x8*)xp;
    bf16x8 yv = *(const bf16x8*)yp;
    float t[8];
    float sum = 0.f, sq = 0.f;
    #pragma unroll
    for (int j = 0; j < 8; j++) {
        t[j] = b2f((uint16_t)xv[j]) + b2f((uint16_t)yv[j]);
        sum += t[j]; sq += t[j] * t[j];
    }
    #pragma unroll
    for (int off = 32; off > 0; off >>= 1) {
        sum += __shfl_xor(sum, off, 64);
        sq  += __shfl_xor(sq,  off, 64);
    }
    const float mean = sum * (1.0f / 512.0f);
    const float var  = sq * (1.0f / 512.0f) - mean * mean;
    const float rs = rsqrtf(var + 1e-5f);
    bf16x8 o;
    #pragma unroll
    for (int j = 0; j < 8; j++) o[j] = (short)f2b((t[j] - mean) * rs);
    *(bf16x8*)xp = o;
}

// ---------------------------------------------------------------- bf16 MFMA GEMM (B^T), BK=64
// 128 x TN tile, 4 waves. Proven round-0 path for the encoder GEMMs (3-4 blocks/CU).
template<int TN, bool GELU>
__global__ __launch_bounds__(256) void gemm_bt_kernel(
    const __hip_bfloat16* __restrict__ A, const __hip_bfloat16* __restrict__ Bt,
    __hip_bfloat16* __restrict__ C, int N, int K) {
    __shared__ uint16_t As[2][128][32];
    __shared__ uint16_t Bs[2][TN][32];
    const int tid = threadIdx.x, w = tid >> 6, lane = tid & 63;
    const int quad = lane >> 4, l15 = lane & 15;
    constexpr int AI = (TN == 128) ? 4 : 2;
    const int wr = (TN == 128) ? (w >> 1) : w;
    const int wc = (TN == 128) ? (w & 1) : 0;
    const int rowbase = wr * (AI * 16);
    int ry, cx;
    swizzle_rc(blockIdx.x, ry, cx);
    const int row0 = ry * 128, col0 = cx * TN;
    const uint16_t* Ag = (const uint16_t*)A;
    const uint16_t* Bg = (const uint16_t*)Bt;
    const int sr = lane >> 2, sc = (lane & 3) * 8;
    f32x4 acc[AI][4];
    #pragma unroll
    for (int i = 0; i < AI; i++)
        #pragma unroll
        for (int j = 0; j < 4; j++) acc[i][j] = {0.f, 0.f, 0.f, 0.f};

    for (int k0 = 0; k0 < K; k0 += 64) {
        #pragma unroll
        for (int h = 0; h < 2; h++) {
            #pragma unroll
            for (int i = 0; i < 2; i++) {
                const int rb = w * 32 + i * 16;
                async_copy16(Ag + (size_t)(row0 + rb + sr) * K + k0 + h * 32 + sc, &As[h][rb][0]);
            }
            if (TN == 128) {
                #pragma unroll
                for (int i = 0; i < 2; i++) {
                    const int rb = w * 32 + i * 16;
                    async_copy16(Bg + (size_t)(col0 + rb + sr) * K + k0 + h * 32 + sc, &Bs[h][rb][0]);
                }
            } else {
                const int rb = w * 16;
                async_copy16(Bg + (size_t)(col0 + rb + sr) * K + k0 + h * 32 + sc, &Bs[h][rb][0]);
            }
        }
        __syncthreads();
        #pragma unroll
        for (int h = 0; h < 2; h++) {
            bf16x8 af[AI], bfr[4];
            #pragma unroll
            for (int i = 0; i < AI; i++)
                af[i] = *(const bf16x8*)&As[h][rowbase + i * 16 + l15][quad * 8];
            #pragma unroll
            for (int j = 0; j < 4; j++)
                bfr[j] = *(const bf16x8*)&Bs[h][wc * 64 + j * 16 + l15][quad * 8];
            #pragma unroll
            for (int i = 0; i < AI; i++)
                #pragma unroll
                for (int j = 0; j < 4; j++)
                    acc[i][j] = __builtin_amdgcn_mfma_f32_16x16x32_bf16(af[i], bfr[j], acc[i][j], 0, 0, 0);
        }
        __syncthreads();
    }
    #pragma unroll
    for (int i = 0; i < AI; i++) {
        #pragma unroll
        for (int r = 0; r < 4; r++) {
            const int row = row0 + rowbase + i * 16 + quad * 4 + r;
            #pragma unroll
            for (int j = 0; j < 4; j++) {
                const int col = col0 + wc * 64 + j * 16 + l15;
                float v = acc[i][j][r];
                if (GELU) v = gelu_f(v);
                C[(size_t)row * N + col] = __float2bfloat16(v);
            }
        }
    }
}

// ---------------------------------------------------------------- MFMA attention (per b,h)
__global__ __launch_bounds__(256) void attn_mfma_kernel(
    const __hip_bfloat16* __restrict__ qkv, const float* __restrict__ log_mask,
    __hip_bfloat16* __restrict__ obuf) {
    constexpr int QS = 72;    // Q/K/P LDS row stride (uint16)
    constexpr int VS32 = 36;  // V^T LDS row stride (uint32 pairs)
    __shared__ uint16_t Qs[64 * QS];
    __shared__ uint16_t Ks_[64 * QS];
    __shared__ uint16_t Ps[64 * QS];
    __shared__ uint32_t Vt32[64 * VS32];   // Vt32[d][sp] = (V[2sp][d], V[2sp+1][d])
    __shared__ float mask_s[64];
    const int b = blockIdx.x >> 3, h = blockIdx.x & 7;
    const int tid = threadIdx.x, w = tid >> 6, lane = tid & 63;
    const int quad = lane >> 4, l15 = lane & 15;
    const uint16_t* qg = (const uint16_t*)qkv;

    if (tid < 64) mask_s[tid] = log_mask[b * 64 + tid];
    // stage Q,K row-major
    #pragma unroll
    for (int it = 0; it < 2; it++) {
        const int idx = it * 256 + tid;          // 0..511
        const int s = idx >> 3, c = (idx & 7) * 8;
        const size_t gbase = (size_t)(b * 64 + s) * 1536 + h * 64 + c;
        *(bf16x8*)&Qs[s * QS + c]  = *(const bf16x8*)&qg[gbase];
        *(bf16x8*)&Ks_[s * QS + c] = *(const bf16x8*)&qg[gbase + 512];
    }
    // stage V transposed, two rows packed per 32-bit word
    {
        const int sp = tid >> 3;                 // 0..31
        const int c = (tid & 7) * 8;
        const size_t gbase = (size_t)(b * 64 + sp * 2) * 1536 + 1024 + h * 64 + c;
        bf16x8 v0 = *(const bf16x8*)&qg[gbase];
        bf16x8 v1 = *(const bf16x8*)&qg[gbase + 1536];
        #pragma unroll
        for (int jj = 0; jj < 8; jj++)
            Vt32[(c + jj) * VS32 + sp] =
                (uint32_t)(uint16_t)v0[jj] | ((uint32_t)(uint16_t)v1[jj] << 16);
    }
    __syncthreads();

    // ---- S = Q K^T for rows w*16..w*16+15
    f32x4 sacc[4];
    #pragma unroll
    for (int j = 0; j < 4; j++) sacc[j] = {0.f, 0.f, 0.f, 0.f};
    #pragma unroll
    for (int k0 = 0; k0 < 2; k0++) {
        bf16x8 aq = *(const bf16x8*)&Qs[(w * 16 + l15) * QS + k0 * 32 + quad * 8];
        #pragma unroll
        for (int j = 0; j < 4; j++) {
            bf16x8 bk = *(const bf16x8*)&Ks_[(j * 16 + l15) * QS + k0 * 32 + quad * 8];
            sacc[j] = __builtin_amdgcn_mfma_f32_16x16x32_bf16(aq, bk, sacc[j], 0, 0, 0);
        }
    }
    // ---- softmax per row; P -> LDS bf16
    #pragma unroll
    for (int r = 0; r < 4; r++) {
        const int q = w * 16 + quad * 4 + r;
        float vals[4];
        float vmax = -3.0e38f;
        #pragma unroll
        for (int j = 0; j < 4; j++) {
            const int col = j * 16 + l15;
            const bool ok = (col <= q) && (mask_s[col] != 0.0f);
            float v = sacc[j][r] * 0.125f + (ok ? 0.0f : NEG_INF);
            vals[j] = v;
            vmax = fmaxf(vmax, v);
        }
        #pragma unroll
        for (int off = 1; off < 16; off <<= 1) vmax = fmaxf(vmax, __shfl_xor(vmax, off, 64));
        float e[4], s = 0.f;
        #pragma unroll
        for (int j = 0; j < 4; j++) { e[j] = __expf(vals[j] - vmax); s += e[j]; }
        #pragma unroll
        for (int off = 1; off < 16; off <<= 1) s += __shfl_xor(s, off, 64);
        const float inv = 1.0f / s;
        #pragma unroll
        for (int j = 0; j < 4; j++)
            Ps[q * QS + j * 16 + l15] = f2b(e[j] * inv);
    }
    __syncthreads();

    // ---- O = P V : B-frags contiguous b128 from Vt32
    f32x4 oacc[4];
    #pragma unroll
    for (int j = 0; j < 4; j++) oacc[j] = {0.f, 0.f, 0.f, 0.f};
    #pragma unroll
    for (int k0 = 0; k0 < 2; k0++) {
        bf16x8 ap = *(const bf16x8*)&Ps[(w * 16 + l15) * QS + k0 * 32 + quad * 8];
        #pragma unroll
        for (int j = 0; j < 4; j++) {
            bf16x8 bv = *(const bf16x8*)&Vt32[(j * 16 + l15) * VS32 + k0 * 16 + quad * 4];
            oacc[j] = __builtin_amdgcn_mfma_f32_16x16x32_bf16(ap, bv, oacc[j], 0, 0, 0);
        }
    }
    #pragma unroll
    for (int r = 0; r < 4; r++) {
        const int q = w * 16 + quad * 4 + r;
        #pragma unroll
        for (int j = 0; j < 4; j++) {
            const int d = j * 16 + l15;
            obuf[(size_t)(b * 64 + q) * 512 + h * 64 + d] = __float2bfloat16(oacc[j][r]);
        }
    }
}

// ---------------------------------------------------------------- persistent 256x256 8-wave 8-phase logits GEMM
// 256 blocks; XCD x = bid&7 owns row band ry in [4x,4x+4); block walks 4-5 tiles.
// 8-phase schedule runs continuously across tile boundaries: on a tile's last
// iteration, P3-P8 stage the NEXT tile's prologue set (slot0 h0/h1 A,B @k=0;
// slot1 h0 A,B @k=64) so the in-flight vmcnt ledger is identical to steady state.
// Epilogue reads acc regs + direct global debias/colmask (no LDS) and overlaps
// with the next tile's in-flight stages.
__global__ __launch_bounds__(512) void logits256_kernel(
    const __hip_bfloat16* __restrict__ A, const __hip_bfloat16* __restrict__ Bt,
    const float* __restrict__ debias, const uint8_t* __restrict__ colmask,
    float* __restrict__ partials) {
    constexpr int K = 512;
    constexpr int NC = NCOLP / 256;      // 33 column tiles
    constexpr int TPX = 4 * NC;          // 132 tiles per XCD
    constexpr int NITER = K >> 7;        // 4
    __shared__ uint16_t SA[2][2][128 * 64];   // [ktile-slot][row-half][row*64 + swz-col]
    __shared__ uint16_t SB[2][2][128 * 64];   // [ktile-slot][col-half][...]

    const int tid = threadIdx.x;
    const int w = tid >> 6, lane = tid & 63;
    const int quad = lane >> 4, l15 = lane & 15;
    const int wr = w >> 2, wc = w & 3;        // 2(M) x 4(N) wave grid, wave = 128x64

    const int x = blockIdx.x & 7, sub = blockIdx.x >> 3;
    int lam = (sub * TPX) >> 5;
    const int lamE = ((sub + 1) * TPX) >> 5;
    if (lam >= lamE) return;

    const uint16_t* Ag = (const uint16_t*)A;
    const uint16_t* Bg = (const uint16_t*)Bt;

    // per-lane staging offsets (element units); LDS dest linear, source inverse-swizzled
    int offS[2][2];
    #pragma unroll
    for (int j = 0; j < 2; j++) {
        const int t = j * 512 + (w << 6) + lane;
        const int r = t >> 3;
        const int s = (t & 7) ^ (r & 7);
        #pragma unroll
        for (int h = 0; h < 2; h++) offS[h][j] = (h * 128 + r) * K + s * 8;
    }
    const int db0 = (w << 6) * 8, db1 = 4096 + (w << 6) * 8;  // LDS dest elem base

    #define STAGE_A(slot, half, base, k0) do { \
        async_copy16(Ag + (base) + offS[half][0] + (k0), &SA[slot][half][db0]); \
        async_copy16(Ag + (base) + offS[half][1] + (k0), &SA[slot][half][db1]); } while (0)
    #define STAGE_B(slot, half, base, k0) do { \
        async_copy16(Bg + (base) + offS[half][0] + (k0), &SB[slot][half][db0]); \
        async_copy16(Bg + (base) + offS[half][1] + (k0), &SB[slot][half][db1]); } while (0)

    // swizzled reads: col-block' = col-block ^ (row&7)
    auto fragA = [&](int slot, int m, int kk) -> bf16x8 {
        return *(const bf16x8*)&SA[slot][wr]
            [((m * 16 + l15) << 6) + ((((kk << 2) + quad) ^ (l15 & 7)) << 3)];
    };
    auto fragB = [&](int slot, int n, int kk) -> bf16x8 {
        return *(const bf16x8*)&SB[slot][wc >> 1]
            [(((wc & 1) * 64 + n * 16 + l15) << 6) + ((((kk << 2) + quad) ^ (l15 & 7)) << 3)];
    };

    // first tile
    int ry = x * 4 + lam / NC, cx = lam % NC;
    size_t baseA = (size_t)(ry * 256) * K;
    size_t baseB = (size_t)(cx * 256) * K;

    f32x4 acc[8][4];
    #pragma unroll
    for (int m = 0; m < 8; m++)
        #pragma unroll
        for (int n = 0; n < 4; n++) acc[m][n] = {0.f, 0.f, 0.f, 0.f};

    // prologue: tile slot0 (4 halves) then slot1 h0's
    STAGE_A(0, 0, baseA, 0); STAGE_A(0, 1, baseA, 0);
    STAGE_B(0, 0, baseB, 0); STAGE_B(0, 1, baseB, 0);
    STAGE_A(1, 0, baseA, 64); STAGE_B(1, 0, baseB, 64);
    VMCNT(4);
    BAR();

    bf16x8 af[4][2], bA[2][2], bB[2][2];
    for (; lam < lamE; ++lam) {
        const bool hasNext = (lam + 1 < lamE);
        int ryn = 0, cxn = 0;
        size_t baseAn = 0, baseBn = 0;
        if (hasNext) {
            ryn = x * 4 + (lam + 1) / NC; cxn = (lam + 1) % NC;
            baseAn = (size_t)(ryn * 256) * K;
            baseBn = (size_t)(cxn * 256) * K;
        }
        for (int it = 0; it < NITER; ++it) {
            const bool lastIt = (it == NITER - 1);
            const bool stC = !lastIt;
            const bool stX = lastIt && hasNext;
            const int kc = it << 7, kn = kc + 128;

            // ---- P1: slot0 m0-3 x n0-1; stage cur slot1 A-h1
            #pragma unroll
            for (int m = 0; m < 4; m++) { af[m][0] = fragA(0, m, 0); af[m][1] = fragA(0, m, 1); }
            #pragma unroll
            for (int n = 0; n < 2; n++) { bA[n][0] = fragB(0, n, 0); bA[n][1] = fragB(0, n, 1); }
            STAGE_A(1, 1, baseA, kc + 64);
            BAR(); LGKM0();
            __builtin_amdgcn_s_setprio(1);
            #pragma unroll
            for (int m = 0; m < 4; m++)
                #pragma unroll
                for (int n = 0; n < 2; n++) {
                    acc[m][n] = __builtin_amdgcn_mfma_f32_16x16x32_bf16(af[m][0], bA[n][0], acc[m][n], 0, 0, 0);
                    acc[m][n] = __builtin_amdgcn_mfma_f32_16x16x32_bf16(af[m][1], bA[n][1], acc[m][n], 0, 0, 0);
                }
            __builtin_amdgcn_s_setprio(0);
            BAR();

            // ---- P2: slot0 m0-3 x n2-3; stage cur slot1 B-h1
            #pragma unroll
            for (int n = 0; n < 2; n++) { bB[n][0] = fragB(0, n + 2, 0); bB[n][1] = fragB(0, n + 2, 1); }
            STAGE_B(1, 1, baseB, kc + 64);
            BAR(); LGKM0();
            __builtin_amdgcn_s_setprio(1);
            #pragma unroll
            for (int m = 0; m < 4; m++)
                #pragma unroll
                for (int n = 0; n < 2; n++) {
                    acc[m][n + 2] = __builtin_amdgcn_mfma_f32_16x16x32_bf16(af[m][0], bB[n][0], acc[m][n + 2], 0, 0, 0);
                    acc[m][n + 2] = __builtin_amdgcn_mfma_f32_16x16x32_bf16(af[m][1], bB[n][1], acc[m][n + 2], 0, 0, 0);
                }
            __builtin_amdgcn_s_setprio(0);
            BAR();

            // ---- P3: slot0 m4-7 x n2-3; stage slot0 B-h0 (cur kn | next 0)
            #pragma unroll
            for (int m = 0; m < 4; m++) { af[m][0] = fragA(0, m + 4, 0); af[m][1] = fragA(0, m + 4, 1); }
            if (stC) STAGE_B(0, 0, baseB, kn); else if (stX) STAGE_B(0, 0, baseBn, 0);
            BAR(); LGKM0();
            __builtin_amdgcn_s_setprio(1);
            #pragma unroll
            for (int m = 0; m < 4; m++)
                #pragma unroll
                for (int n = 0; n < 2; n++) {
                    acc[m + 4][n + 2] = __builtin_amdgcn_mfma_f32_16x16x32_bf16(af[m][0], bB[n][0], acc[m + 4][n + 2], 0, 0, 0);
                    acc[m + 4][n + 2] = __builtin_amdgcn_mfma_f32_16x16x32_bf16(af[m][1], bB[n][1], acc[m + 4][n + 2], 0, 0, 0);
                }
            __builtin_amdgcn_s_setprio(0);
            BAR();

            // ---- P4: slot0 m4-7 x n0-1 (regs only); stage slot0 A-h0; vmcnt gate
            if (stC) STAGE_A(0, 0, baseA, kn); else if (stX) STAGE_A(0, 0, baseAn, 0);
            __builtin_amdgcn_s_setprio(1);
            #pragma unroll
            for (int m = 0; m < 4; m++)
                #pragma unroll
                for (int n = 0; n < 2; n++) {
                    acc[m + 4][n] = __builtin_amdgcn_mfma_f32_16x16x32_bf16(af[m][0], bA[n][0], acc[m + 4][n], 0, 0, 0);
                    acc[m + 4][n] = __builtin_amdgcn_mfma_f32_16x16x32_bf16(af[m][1], bA[n][1], acc[m + 4][n], 0, 0, 0);
                }
            __builtin_amdgcn_s_setprio(0);
            if (stC || stX) { VMCNT(4); } else { VMCNT(0); }  // cur slot1 fully landed
            BAR();

            // ---- P5: slot1 m0-3 x n0-1; stage slot0 A-h1
            #pragma unroll
            for (int m = 0; m < 4; m++) { af[m][0] = fragA(1, m, 0); af[m][1] = fragA(1, m, 1); }
            #pragma unroll
            for (int n = 0; n < 2; n++) { bA[n][0] = fragB(1, n, 0); bA[n][1] = fragB(1, n, 1); }
            if (stC) STAGE_A(0, 1, baseA, kn); else if (stX) STAGE_A(0, 1, baseAn, 0);
            BAR(); LGKM0();
            __builtin_amdgcn_s_setprio(1);
            #pragma unroll
            for (int m = 0; m < 4; m++)
                #pragma unroll
                for (int n = 0; n < 2; n++) {
                    acc[m][n] = __builtin_amdgcn_mfma_f32_16x16x32_bf16(af[m][0], bA[n][0], acc[m][n], 0, 0, 0);
                    acc[m][n] = __builtin_amdgcn_mfma_f32_16x16x32_bf16(af[m][1], bA[n][1], acc[m][n], 0, 0, 0);
                }
            __builtin_amdgcn_s_setprio(0);
            BAR();

            // ---- P6: slot1 m0-3 x n2-3; stage slot0 B-h1
            #pragma unroll
            for (int n = 0; n < 2; n++) { bB[n][0] = fragB(1, n + 2, 0); bB[n][1] = fragB(1, n + 2, 1); }
            if (stC) STAGE_B(0, 1, baseB, kn); else if (stX) STAGE_B(0, 1, baseBn, 0);
            BAR(); LGKM0();
            __builtin_amdgcn_s_setprio(1);
            #pragma unroll
            for (int m = 0; m < 4; m++)
                #pragma unroll
                for (int n = 0; n < 2; n++) {
                    acc[m][n + 2] = __builtin_amdgcn_mfma_f32_16x16x32_bf16(af[m][0], bB[n][0], acc[m][n + 2], 0, 0, 0);
                    acc[m][n + 2] = __builtin_amdgcn_mfma_f32_16x16x32_bf16(af[m][1], bB[n][1], acc[m][n + 2], 0, 0, 0);
                }
            __builtin_amdgcn_s_setprio(0);
            BAR();

            // ---- P7: slot1 m4-7 x n2-3; stage slot1 B-h0 (cur kn+64 | next 64)
            #pragma unroll
            for (int m = 0; m < 4; m++) { af[m][0] = fragA(1, m + 4, 0); af[m][1] = fragA(1, m + 4, 1); }
            if (stC) STAGE_B(1, 0, baseB, kn + 64); else if (stX) STAGE_B(1, 0, baseBn, 64);
            BAR(); LGKM0();
            __builtin_amdgcn_s_setprio(1);
            #pragma unroll
            for (int m = 0; m < 4; m++)
                #pragma unroll
                for (int n = 0; n < 2; n++) {
                    acc[m + 4][n + 2] = __builtin_amdgcn_mfma_f32_16x16x32_bf16(af[m][0], bB[n][0], acc[m + 4][n + 2], 0, 0, 0);
                    acc[m + 4][n + 2] = __builtin_amdgcn_mfma_f32_16x16x32_bf16(af[m][1], bB[n][1], acc[m + 4][n + 2], 0, 0, 0);
                }
            __builtin_amdgcn_s_setprio(0);
            BAR();

            // ---- P8: slot1 m4-7 x n0-1 (regs only); stage slot1 A-h0; vmcnt gate
            if (stC) STAGE_A(1, 0, baseA, kn + 64); else if (stX) STAGE_A(1, 0, baseAn, 64);
            __builtin_amdgcn_s_setprio(1);
            #pragma unroll
            for (int m = 0; m < 4; m++)
                #pragma unroll
                for (int n = 0; n < 2; n++) {
                    acc[m + 4][n] = __builtin_amdgcn_mfma_f32_16x16x32_bf16(af[m][0], bA[n][0], acc[m + 4][n], 0, 0, 0);
                    acc[m + 4][n] = __builtin_amdgcn_mfma_f32_16x16x32_bf16(af[m][1], bA[n][1], acc[m + 4][n], 0, 0, 0);
                }
            __builtin_amdgcn_s_setprio(0);
            if (stC || stX) { VMCNT(4); BAR(); }   // next slot0 fully landed
        }

        // ---------------- per-tile epilogue (regs + direct global loads; no LDS)
        {
            const int strip = cx * 4 + wc;
            const int col0 = cx * 256;
            float deb[4]; uint8_t cmv[2][4];
            #pragma unroll
            for (int n = 0; n < 4; n++) {
                const int lcol = wc * 64 + n * 16 + l15;
                deb[n] = debias[col0 + lcol] + CMAX;
                cmv[0][n] = colmask[(size_t)(ry * 4 + wr * 2 + 0) * NCOLP + col0 + lcol];
                cmv[1][n] = colmask[(size_t)(ry * 4 + wr * 2 + 1) * NCOLP + col0 + lcol];
            }
            #pragma unroll
            for (int m = 0; m < 8; m++) {
                #pragma unroll
                for (int r = 0; r < 4; r++) {
                    const int row = ry * 256 + wr * 128 + m * 16 + quad * 4 + r;
                    float s = 0.f;
                    #pragma unroll
                    for (int n = 0; n < 4; n++) {
                        float t = acc[m][n][r] - deb[n];           // = v - deb - CMAX
                        t = (cmv[m >> 2][n] != 0) ? -1.0e30f : t;
                        s += __expf(t);
                    }
                    #pragma unroll
                    for (int off = 1; off < 16; off <<= 1) s += __shfl_xor(s, off, 64);
                    if (l15 == 0) partials[(size_t)row * NSTRIP + strip] = s;
                }
            }
            #pragma unroll
            for (int m = 0; m < 8; m++)
                #pragma unroll
                for (int n = 0; n < 4; n++) acc[m][n] = {0.f, 0.f, 0.f, 0.f};
        }
        ry = ryn; cx = cxn; baseA = baseAn; baseB = baseBn;
    }
    #undef STAGE_A
    #undef STAGE_B
}

// ---------------------------------------------------------------- label logits (wave per row)
__global__ __launch_bounds__(256) void label_kernel(
    const __hip_bfloat16* __restrict__ xb, const __hip_bfloat16* __restrict__ sebf,
    const float* __restrict__ debias, const uint8_t* __restrict__ padcol,
    float* __restrict__ lab) {
    const int w = threadIdx.x >> 6, lane = threadIdx.x & 63;
    const int row = blockIdx.x * 4 + w;            // 0..8191
    const int b = row >> 6, s0 = row & 63;
    const int k = b * 65 + s0 + 1;
    const uint16_t* xp = (const uint16_t*)xb + (size_t)row * DIM + lane * 8;
    const uint16_t* sp = (const uint16_t*)sebf + (size_t)k * DIM + lane * 8;
    bf16x8 xv = *(const bf16x8*)xp;
    bf16x8 sv = *(const bf16x8*)sp;
    float a = 0.f;
    #pragma unroll
    for (int j = 0; j < 8; j++) a += b2f((uint16_t)xv[j]) * b2f((uint16_t)sv[j]);
    #pragma unroll
    for (int off = 32; off > 0; off >>= 1) a += __shfl_xor(a, off, 64);
    if (lane == 0)
        lab[row] = padcol[k] ? NEG_INF : (a - debias[k]);
}

// ---------------------------------------------------------------- combine + reduce
__global__ __launch_bounds__(256) void combine_kernel(
    const float* __restrict__ partials, const float* __restrict__ label_logit,
    const float* __restrict__ log_mask, float* __restrict__ bsums) {
    const int row = blockIdx.x * 256 + threadIdx.x;
    const float lab = label_logit[row];
    // label column is colmask'd in the GEMM; re-add its exp term here
    float Ls = __expf(lab - CMAX);
    const float4* pr = (const float4*)(partials + (size_t)row * NSTRIP);
    for (int t = 0; t < NSTRIP / 4; t++) {
        float4 v = pr[t];
        Ls += v.x + v.y + v.z + v.w;
    }
    const float lse = CMAX + logf(Ls);
    const float valid = (log_mask[row] != 0.0f) ? 1.0f : 0.0f;
    float a = (lse - lab) * valid;
    float c = valid;
    __shared__ float sa[4], sc_[4];
    #pragma unroll
    for (int off = 32; off > 0; off >>= 1) {
        a += __shfl_down(a, off, 64);
        c += __shfl_down(c, off, 64);
    }
    const int lane = threadIdx.x & 63, w = threadIdx.x >> 6;
    if (lane == 0) { sa[w] = a; sc_[w] = c; }
    __syncthreads();
    if (threadIdx.x == 0) {
        bsums[blockIdx.x * 2 + 0] = sa[0] + sa[1] + sa[2] + sa[3];
        bsums[blockIdx.x * 2 + 1] = sc_[0] + sc_[1] + sc_[2] + sc_[3];
    }
}

__global__ __launch_bounds__(64) void finalize_kernel(
    const float* __restrict__ bsums, float* __restrict__ out) {
    const int t = threadIdx.x;
    float a = 0.f, c = 0.f;
    if (t < 32) { a = bsums[2 * t]; c = bsums[2 * t + 1]; }
    #pragma unroll
    for (int off = 32; off > 0; off >>= 1) {
        a += __shfl_down(a, off, 64);
        c += __shfl_down(c, off, 64);
    }
    if (t == 0) out[0] = a / c;
}

// ---------------------------------------------------------------- launch
extern "C" void kernel_launch(void* const* d_in, const int* in_sizes, int n_in,
                              void* d_out, int out_size, void* d_ws, size_t ws_size,
                              hipStream_t stream) {
    const int*   ids    = (const int*)d_in[0];
    const float* lm     = (const float*)d_in[1];
    const float* emb    = (const float*)d_in[2];
    const float* pos    = (const float*)d_in[3];
    const float* qkv_w  = (const float*)d_in[4];
    const float* out_w  = (const float*)d_in[5];
    const float* ffn1_w = (const float*)d_in[6];
    const float* ffn2_w = (const float*)d_in[7];
    const float* pop    = (const float*)d_in[8];
    float* out = (float*)d_out;

    char* p = (char*)d_ws;
    auto alloc = [&](size_t bytes) {
        char* r = p;
        p += (bytes + 255) & ~(size_t)255;
        return r;
    };
    typedef __hip_bfloat16 bf16;
    bf16*    sebf     = (bf16*)alloc((size_t)NCOLP * DIM * 2);       // 8.65 MB (padded)
    float*   debias   = (float*)alloc((size_t)NCOLP * 4);
    uint8_t* padcol   = (uint8_t*)alloc(NCOLP);
    uint8_t* colmask  = (uint8_t*)alloc((size_t)BSZ * NCOLP);        // 1.08 MB (padded)
    bf16*    xb       = (bf16*)alloc((size_t)NROW * DIM * 2);        // 8.4 MB (residual)
    bf16*    big      = (bf16*)alloc((size_t)NROW * 2048 * 2);       // 33.6 MB (qkv / h)
    bf16*    tmp1     = (bf16*)alloc((size_t)NROW * DIM * 2);        // attn out
    bf16*    tmp2     = (bf16*)alloc((size_t)NROW * DIM * 2);        // proj / f2
    float*   partials = (float*)alloc((size_t)NROW * NSTRIP * 4);    // 4.3 MB
    float*   lab      = (float*)alloc((size_t)NROW * 4);
    float*   bsums    = (float*)alloc(64 * 4);
    bf16*    qkvT     = (bf16*)alloc((size_t)NLAYER * 1536 * 512 * 2);
    bf16*    outT     = (bf16*)alloc((size_t)NLAYER * 512 * 512 * 2);
    bf16*    f1T      = (bf16*)alloc((size_t)NLAYER * 2048 * 512 * 2);
    bf16*    f2T      = (bf16*)alloc((size_t)NLAYER * 512 * 2048 * 2);

    transpose_bf16_kernel<<<dim3(1536 / 32, 512 / 32, NLAYER), 256, 0, stream>>>(
        qkv_w, qkvT, 512, 1536);
    transpose_bf16_kernel<<<dim3(512 / 32, 512 / 32, NLAYER), 256, 0, stream>>>(
        out_w, outT, 512, 512);
    transpose_bf16_kernel<<<dim3(2048 / 32, 512 / 32, NLAYER), 256, 0, stream>>>(
        ffn1_w, f1T, 512, 2048);
    transpose_bf16_kernel<<<dim3(512 / 32, 2048 / 32, NLAYER), 256, 0, stream>>>(
        ffn2_w, f2T, 2048, 512);

    gather_posln_kernel<<<NCOL / 4, 256, 0, stream>>>(ids, emb, pop, pos, sebf, debias, xb);
    mask_kernel<<<BSZ * 8, 256, 0, stream>>>(ids, lm, colmask, padcol);

    for (int l = 0; l < NLAYER; l++) {
        gemm_bt_kernel<128, false><<<(1536 / 128) * 64, 256, 0, stream>>>(
            xb, qkvT + (size_t)l * 1536 * 512, big, 1536, 512);
        attn_mfma_kernel<<<BSZ * HEADS, 256, 0, stream>>>(big, lm, tmp1);
        gemm_bt_kernel<64, false><<<(512 / 64) * 64, 256, 0, stream>>>(
            tmp1, outT + (size_t)l * 512 * 512, tmp2, 512, 512);
        resid_ln_kernel<<<NROW / 4, 256, 0, stream>>>(xb, tmp2);
        gemm_bt_kernel<128, true><<<(2048 / 128) * 64, 256, 0, stream>>>(
            xb, f1T + (size_t)l * 2048 * 512, big, 2048, 512);
        gemm_bt_kernel<64, false><<<(512 / 64) * 64, 256, 0, stream>>>(
            big, f2T + (size_t)l * 512 * 2048, tmp2, 512, 2048);
        resid_ln_kernel<<<NROW / 4, 256, 0, stream>>>(xb, tmp2);
    }

    label_kernel<<<NROW / 4, 256, 0, stream>>>(xb, sebf, debias, padcol, lab);
    logits256_kernel<<<256, 512, 0, stream>>>(xb, sebf, debias, colmask, partials);
    combine_kernel<<<NROW / 256, 256, 0, stream>>>(partials, lab, lm, bsums);
    finalize_kernel<<<1, 64, 0, stream>>>(bsums, out);
}

// Round 4
// 628.149 us; speedup vs baseline: 1.1586x; 1.0697x over previous
//
#include <hip/hip_runtime.h>
#include <hip/hip_bf16.h>
#include <cstdint>
#include <cstddef>

#define NEG_INF -10000.0f

constexpr int BSZ  = 128;
constexpr int SEQ  = 64;     // L
constexpr int DIM  = 512;    // D
constexpr int HEADS = 8;
constexpr int NLAYER = 2;
constexpr int NCOL = BSZ * (SEQ + 1);   // 8320
constexpr int NCOLP = 8448;             // padded to 33*256 for 256-wide tiles
constexpr int NROW = BSZ * SEQ;         // 8192
constexpr int NSTRIP = NCOLP / 64;      // 132
constexpr float CMAX = 40.0f;           // analytic upper bound (max logit < 28)
constexpr float LOG2E = 1.4426950408889634f;

typedef __attribute__((ext_vector_type(8))) short bf16x8;   // 8 bf16 in 4 VGPRs
typedef __attribute__((ext_vector_type(4))) float f32x4;

// async global->LDS, 16B per lane, dest = ldsbase + lane*16
__device__ __forceinline__ void async_copy16(const void* g, void* l) {
    __builtin_amdgcn_global_load_lds(
        (const __attribute__((address_space(1))) void*)g,
        (__attribute__((address_space(3))) void*)l, 16, 0, 0);
}

__device__ __forceinline__ float b2f(uint16_t u) {
    return __builtin_bit_cast(float, (uint32_t)u << 16);
}
__device__ __forceinline__ uint16_t f2b(float f) {
    __hip_bfloat16 h = __float2bfloat16(f);
    return __builtin_bit_cast(uint16_t, h);
}

// raw v_exp_f32 (exp2) — single instruction, no libm guards
__device__ __forceinline__ float fexp2(float x) {
    float r; asm("v_exp_f32 %0, %1" : "=v"(r) : "v"(x)); return r;
}

// fast tanh-gelu: tanh(u) = 1 - 2/(e^{2u}+1), e^{2u} = exp2(2u*log2e)
__device__ __forceinline__ float gelu_f(float v) {
    float u = 0.7978845608028654f * (v + 0.044715f * v * v * v);
    float t2 = fexp2(u * (2.0f * LOG2E));
    float th = 1.0f - 2.0f * __builtin_amdgcn_rcpf(t2 + 1.0f);
    return 0.5f * v * (1.0f + th);
}

// XCD-aware swizzle for the 128-tile GEMM (64 row-blocks of 128 rows).
__device__ __forceinline__ void swizzle_rc(int id, int& ry, int& cx) {
    ry = (id & 7) * 8 + ((id >> 3) & 7);
    cx = id >> 6;
}

#define BAR() __builtin_amdgcn_s_barrier()
#define LGKM0() asm volatile("s_waitcnt lgkmcnt(0)" ::: "memory")
#define VMCNT(n) asm volatile("s_waitcnt vmcnt(" #n ")" ::: "memory")

// ---------------------------------------------------------------- gather + pos + LN (wave per row)
__global__ __launch_bounds__(256) void gather_posln_kernel(
    const int* __restrict__ ids, const float* __restrict__ table,
    const float* __restrict__ pop, const float* __restrict__ pos,
    __hip_bfloat16* __restrict__ sebf, float* __restrict__ debias,
    float* __restrict__ deb2, __hip_bfloat16* __restrict__ xb) {
    const int w = threadIdx.x >> 6, lane = threadIdx.x & 63;
    const int k = blockIdx.x * 4 + w;              // 0..8319
    const int b = k / 65, s = k - b * 65;
    const int id = ids[k];
    const float* src = table + (size_t)id * DIM + lane * 8;
    float4 u0 = *(const float4*)src;
    float4 u1 = *(const float4*)(src + 4);
    float v[8] = {u0.x, u0.y, u0.z, u0.w, u1.x, u1.y, u1.z, u1.w};
    bf16x8 se;
    #pragma unroll
    for (int j = 0; j < 8; j++) se[j] = (short)f2b(v[j]);
    *(bf16x8*)((uint16_t*)sebf + (size_t)k * DIM + lane * 8) = se;
    if (lane == 0) {
        const float lp = logf(pop[id]);
        debias[k] = lp;
        deb2[k] = (lp + CMAX) * LOG2E;
    }
    if (s < 64) {
        const float* pp = pos + (size_t)s * DIM + lane * 8;
        float4 p0 = *(const float4*)pp;
        float4 p1 = *(const float4*)(pp + 4);
        float t[8] = {v[0] + p0.x, v[1] + p0.y, v[2] + p0.z, v[3] + p0.w,
                      v[4] + p1.x, v[5] + p1.y, v[6] + p1.z, v[7] + p1.w};
        float sum = 0.f, sq = 0.f;
        #pragma unroll
        for (int j = 0; j < 8; j++) { sum += t[j]; sq += t[j] * t[j]; }
        #pragma unroll
        for (int off = 32; off > 0; off >>= 1) {
            sum += __shfl_xor(sum, off, 64);
            sq  += __shfl_xor(sq,  off, 64);
        }
        const float mean = sum * (1.0f / 512.0f);
        const float var  = sq * (1.0f / 512.0f) - mean * mean;
        const float rs = rsqrtf(var + 1e-5f);
        bf16x8 o;
        #pragma unroll
        for (int j = 0; j < 8; j++) o[j] = (short)f2b((t[j] - mean) * rs);
        *(bf16x8*)((uint16_t*)xb + (size_t)(b * 64 + s) * DIM + lane * 8) = o;
    }
}

// ---------------------------------------------------------------- masks (padded to NCOLP)
__global__ __launch_bounds__(256) void mask_kernel(
    const int* __restrict__ ids, const float* __restrict__ log_mask,
    uint8_t* __restrict__ colmask, uint8_t* __restrict__ padcol) {
    const int bi = blockIdx.x >> 3, seg = blockIdx.x & 7;
    __shared__ int sid[65];
    if (threadIdx.x < 65) sid[threadIdx.x] = ids[bi * 65 + threadIdx.x];
    __syncthreads();
    const int kend = (seg + 1) * (NCOLP / 8);
    for (int k = seg * (NCOLP / 8) + threadIdx.x; k < kend; k += 256) {
        uint8_t cmv, pcv;
        if (k < NCOL) {
            const int id = ids[k];
            bool mem = false;
            #pragma unroll
            for (int j = 0; j < 65; j++) mem |= (sid[j] == id);
            const int i2 = k / 65, jj = k - i2 * 65;
            const bool pc = (jj < 64) && (log_mask[i2 * 64 + jj] == 0.0f);
            cmv = (mem || pc) ? 1 : 0;
            pcv = pc ? 1 : 0;
        } else { cmv = 1; pcv = 1; }   // padded columns always masked
        colmask[(size_t)bi * NCOLP + k] = cmv;
        if (bi == 0) padcol[k] = pcv;
    }
}

// ---------------------------------------------------------------- weight transpose+cast
__global__ __launch_bounds__(256) void transpose_bf16_kernel(
    const float* __restrict__ W, __hip_bfloat16* __restrict__ WT, int K, int N) {
    __shared__ float tile[32][33];
    const size_t loff = (size_t)blockIdx.z * K * N;
    const int nt = blockIdx.x * 32, kt = blockIdx.y * 32;
    const int c = threadIdx.x & 31, r = threadIdx.x >> 5;
    #pragma unroll
    for (int p = 0; p < 4; p++)
        tile[p * 8 + r][c] = W[loff + (size_t)(kt + p * 8 + r) * N + nt + c];
    __syncthreads();
    #pragma unroll
    for (int p = 0; p < 4; p++)
        WT[loff + (size_t)(nt + p * 8 + r) * K + kt + c] = __float2bfloat16(tile[c][p * 8 + r]);
}

// ---------------------------------------------------------------- residual + LN (wave per row, bf16)
// SCALED: also write LN(x)*log2e to xs (A-matrix for the exp2-folded logits GEMM)
template<bool SCALED>
__global__ __launch_bounds__(256) void resid_ln_kernel(
    __hip_bfloat16* __restrict__ xb, const __hip_bfloat16* __restrict__ y,
    __hip_bfloat16* __restrict__ xs) {
    const int w = threadIdx.x >> 6, lane = threadIdx.x & 63;
    const int row = blockIdx.x * 4 + w;
    uint16_t* xp = (uint16_t*)xb + (size_t)row * DIM + lane * 8;
    const uint16_t* yp = (const uint16_t*)y + (size_t)row * DIM + lane * 8;
    bf16x8 xv = *(const bf16x8*)xp;
    bf16x8 yv = *(const bf16x8*)yp;
    float t[8];
    float sum = 0.f, sq = 0.f;
    #pragma unroll
    for (int j = 0; j < 8; j++) {
        t[j] = b2f((uint16_t)xv[j]) + b2f((uint16_t)yv[j]);
        sum += t[j]; sq += t[j] * t[j];
    }
    #pragma unroll
    for (int off = 32; off > 0; off >>= 1) {
        sum += __shfl_xor(sum, off, 64);
        sq  += __shfl_xor(sq,  off, 64);
    }
    const float mean = sum * (1.0f / 512.0f);
    const float var  = sq * (1.0f / 512.0f) - mean * mean;
    const float rs = rsqrtf(var + 1e-5f);
    bf16x8 o;
    #pragma unroll
    for (int j = 0; j < 8; j++) o[j] = (short)f2b((t[j] - mean) * rs);
    *(bf16x8*)xp = o;
    if (SCALED) {
        bf16x8 os;
        #pragma unroll
        for (int j = 0; j < 8; j++) os[j] = (short)f2b((t[j] - mean) * rs * LOG2E);
        *(bf16x8*)((uint16_t*)xs + (size_t)row * DIM + lane * 8) = os;
    }
}

// ---------------------------------------------------------------- bf16 MFMA GEMM (B^T), BK=64
// 128 x TN tile, 4 waves. Proven encoder path (3-4 blocks/CU).
template<int TN, bool GELU>
__global__ __launch_bounds__(256) void gemm_bt_kernel(
    const __hip_bfloat16* __restrict__ A, const __hip_bfloat16* __restrict__ Bt,
    __hip_bfloat16* __restrict__ C, int N, int K) {
    __shared__ uint16_t As[2][128][32];
    __shared__ uint16_t Bs[2][TN][32];
    const int tid = threadIdx.x, w = tid >> 6, lane = tid & 63;
    const int quad = lane >> 4, l15 = lane & 15;
    constexpr int AI = (TN == 128) ? 4 : 2;
    const int wr = (TN == 128) ? (w >> 1) : w;
    const int wc = (TN == 128) ? (w & 1) : 0;
    const int rowbase = wr * (AI * 16);
    int ry, cx;
    swizzle_rc(blockIdx.x, ry, cx);
    const int row0 = ry * 128, col0 = cx * TN;
    const uint16_t* Ag = (const uint16_t*)A;
    const uint16_t* Bg = (const uint16_t*)Bt;
    const int sr = lane >> 2, sc = (lane & 3) * 8;
    f32x4 acc[AI][4];
    #pragma unroll
    for (int i = 0; i < AI; i++)
        #pragma unroll
        for (int j = 0; j < 4; j++) acc[i][j] = {0.f, 0.f, 0.f, 0.f};

    for (int k0 = 0; k0 < K; k0 += 64) {
        #pragma unroll
        for (int h = 0; h < 2; h++) {
            #pragma unroll
            for (int i = 0; i < 2; i++) {
                const int rb = w * 32 + i * 16;
                async_copy16(Ag + (size_t)(row0 + rb + sr) * K + k0 + h * 32 + sc, &As[h][rb][0]);
            }
            if (TN == 128) {
                #pragma unroll
                for (int i = 0; i < 2; i++) {
                    const int rb = w * 32 + i * 16;
                    async_copy16(Bg + (size_t)(col0 + rb + sr) * K + k0 + h * 32 + sc, &Bs[h][rb][0]);
                }
            } else {
                const int rb = w * 16;
                async_copy16(Bg + (size_t)(col0 + rb + sr) * K + k0 + h * 32 + sc, &Bs[h][rb][0]);
            }
        }
        __syncthreads();
        #pragma unroll
        for (int h = 0; h < 2; h++) {
            bf16x8 af[AI], bfr[4];
            #pragma unroll
            for (int i = 0; i < AI; i++)
                af[i] = *(const bf16x8*)&As[h][rowbase + i * 16 + l15][quad * 8];
            #pragma unroll
            for (int j = 0; j < 4; j++)
                bfr[j] = *(const bf16x8*)&Bs[h][wc * 64 + j * 16 + l15][quad * 8];
            #pragma unroll
            for (int i = 0; i < AI; i++)
                #pragma unroll
                for (int j = 0; j < 4; j++)
                    acc[i][j] = __builtin_amdgcn_mfma_f32_16x16x32_bf16(af[i], bfr[j], acc[i][j], 0, 0, 0);
        }
        __syncthreads();
    }
    #pragma unroll
    for (int i = 0; i < AI; i++) {
        #pragma unroll
        for (int r = 0; r < 4; r++) {
            const int row = row0 + rowbase + i * 16 + quad * 4 + r;
            #pragma unroll
            for (int j = 0; j < 4; j++) {
                const int col = col0 + wc * 64 + j * 16 + l15;
                float v = acc[i][j][r];
                if (GELU) v = gelu_f(v);
                C[(size_t)row * N + col] = __float2bfloat16(v);
            }
        }
    }
}

// ---------------------------------------------------------------- MFMA attention (per b,h)
__global__ __launch_bounds__(256) void attn_mfma_kernel(
    const __hip_bfloat16* __restrict__ qkv, const float* __restrict__ log_mask,
    __hip_bfloat16* __restrict__ obuf) {
    constexpr int QS = 72;    // Q/K/P LDS row stride (uint16)
    constexpr int VS32 = 36;  // V^T LDS row stride (uint32 pairs)
    __shared__ uint16_t Qs[64 * QS];
    __shared__ uint16_t Ks_[64 * QS];
    __shared__ uint16_t Ps[64 * QS];
    __shared__ uint32_t Vt32[64 * VS32];   // Vt32[d][sp] = (V[2sp][d], V[2sp+1][d])
    __shared__ float mask_s[64];
    const int b = blockIdx.x >> 3, h = blockIdx.x & 7;
    const int tid = threadIdx.x, w = tid >> 6, lane = tid & 63;
    const int quad = lane >> 4, l15 = lane & 15;
    const uint16_t* qg = (const uint16_t*)qkv;

    if (tid < 64) mask_s[tid] = log_mask[b * 64 + tid];
    // stage Q,K row-major
    #pragma unroll
    for (int it = 0; it < 2; it++) {
        const int idx = it * 256 + tid;          // 0..511
        const int s = idx >> 3, c = (idx & 7) * 8;
        const size_t gbase = (size_t)(b * 64 + s) * 1536 + h * 64 + c;
        *(bf16x8*)&Qs[s * QS + c]  = *(const bf16x8*)&qg[gbase];
        *(bf16x8*)&Ks_[s * QS + c] = *(const bf16x8*)&qg[gbase + 512];
    }
    // stage V transposed, two rows packed per 32-bit word
    {
        const int sp = tid >> 3;                 // 0..31
        const int c = (tid & 7) * 8;
        const size_t gbase = (size_t)(b * 64 + sp * 2) * 1536 + 1024 + h * 64 + c;
        bf16x8 v0 = *(const bf16x8*)&qg[gbase];
        bf16x8 v1 = *(const bf16x8*)&qg[gbase + 1536];
        #pragma unroll
        for (int jj = 0; jj < 8; jj++)
            Vt32[(c + jj) * VS32 + sp] =
                (uint32_t)(uint16_t)v0[jj] | ((uint32_t)(uint16_t)v1[jj] << 16);
    }
    __syncthreads();

    // ---- S = Q K^T for rows w*16..w*16+15
    f32x4 sacc[4];
    #pragma unroll
    for (int j = 0; j < 4; j++) sacc[j] = {0.f, 0.f, 0.f, 0.f};
    #pragma unroll
    for (int k0 = 0; k0 < 2; k0++) {
        bf16x8 aq = *(const bf16x8*)&Qs[(w * 16 + l15) * QS + k0 * 32 + quad * 8];
        #pragma unroll
        for (int j = 0; j < 4; j++) {
            bf16x8 bk = *(const bf16x8*)&Ks_[(j * 16 + l15) * QS + k0 * 32 + quad * 8];
            sacc[j] = __builtin_amdgcn_mfma_f32_16x16x32_bf16(aq, bk, sacc[j], 0, 0, 0);
        }
    }
    // ---- softmax per row; P -> LDS bf16
    #pragma unroll
    for (int r = 0; r < 4; r++) {
        const int q = w * 16 + quad * 4 + r;
        float vals[4];
        float vmax = -3.0e38f;
        #pragma unroll
        for (int j = 0; j < 4; j++) {
            const int col = j * 16 + l15;
            const bool ok = (col <= q) && (mask_s[col] != 0.0f);
            float v = sacc[j][r] * 0.125f + (ok ? 0.0f : NEG_INF);
            vals[j] = v;
            vmax = fmaxf(vmax, v);
        }
        #pragma unroll
        for (int off = 1; off < 16; off <<= 1) vmax = fmaxf(vmax, __shfl_xor(vmax, off, 64));
        float e[4], s = 0.f;
        #pragma unroll
        for (int j = 0; j < 4; j++) { e[j] = fexp2((vals[j] - vmax) * LOG2E); s += e[j]; }
        #pragma unroll
        for (int off = 1; off < 16; off <<= 1) s += __shfl_xor(s, off, 64);
        const float inv = 1.0f / s;
        #pragma unroll
        for (int j = 0; j < 4; j++)
            Ps[q * QS + j * 16 + l15] = f2b(e[j] * inv);
    }
    __syncthreads();

    // ---- O = P V : B-frags contiguous b128 from Vt32
    f32x4 oacc[4];
    #pragma unroll
    for (int j = 0; j < 4; j++) oacc[j] = {0.f, 0.f, 0.f, 0.f};
    #pragma unroll
    for (int k0 = 0; k0 < 2; k0++) {
        bf16x8 ap = *(const bf16x8*)&Ps[(w * 16 + l15) * QS + k0 * 32 + quad * 8];
        #pragma unroll
        for (int j = 0; j < 4; j++) {
            bf16x8 bv = *(const bf16x8*)&Vt32[(j * 16 + l15) * VS32 + k0 * 16 + quad * 4];
            oacc[j] = __builtin_amdgcn_mfma_f32_16x16x32_bf16(ap, bv, oacc[j], 0, 0, 0);
        }
    }
    #pragma unroll
    for (int r = 0; r < 4; r++) {
        const int q = w * 16 + quad * 4 + r;
        #pragma unroll
        for (int j = 0; j < 4; j++) {
            const int d = j * 16 + l15;
            obuf[(size_t)(b * 64 + q) * 512 + h * 64 + d] = __float2bfloat16(oacc[j][r]);
        }
    }
}

// ---------------------------------------------------------------- 256x256 8-wave 8-phase logits GEMM
// R1's best-measured config (124 us). A is pre-scaled by log2e; deb2 pre-folded;
// epilogue is sub + cndmask + raw v_exp_f32 + add.
__global__ __launch_bounds__(512) void gemm256_logits_kernel(
    const __hip_bfloat16* __restrict__ A, const __hip_bfloat16* __restrict__ Bt,
    int N, int K,
    const float* __restrict__ deb2, const uint8_t* __restrict__ colmask,
    float* __restrict__ partials) {
    __shared__ uint16_t SA[2][2][128 * 64];   // [ktile-slot][half][row*64 + swz-col]
    __shared__ uint16_t SB[2][2][128 * 64];
    __shared__ float dc_s[256];
    __shared__ uint8_t cm_s[4][256];

    const int tid = threadIdx.x;
    const int w = tid >> 6, lane = tid & 63;
    const int quad = lane >> 4, l15 = lane & 15;
    const int wr = w >> 2, wc = w & 3;        // 2(M) x 4(N) wave grid, wave = 128x64

    const int nwg = gridDim.x;
    const int xid = (blockIdx.x & 7) * (nwg >> 3) + (blockIdx.x >> 3);  // XCD swizzle
    const int ry = xid & 31, cx = xid >> 5;
    const int row0 = ry * 256, col0 = cx * 256;

    const uint16_t* Ag = (const uint16_t*)A;
    const uint16_t* Bg = (const uint16_t*)Bt;

    if (tid < 256) dc_s[tid] = deb2[col0 + tid];
    #pragma unroll
    for (int j = 0; j < 2; j++) {
        const int e = j * 512 + tid;
        cm_s[e >> 8][e & 255] =
            colmask[(size_t)((row0 >> 6) + (e >> 8)) * NCOLP + col0 + (e & 255)];
    }

    // per-lane swizzled staging source pointers; LDS dest stays linear
    const int tb0 = w << 6, tb1 = 512 + (w << 6);
    const uint16_t* gA[2][2];
    const uint16_t* gB[2][2];
    #pragma unroll
    for (int j = 0; j < 2; j++) {
        const int t = j * 512 + (w << 6) + lane;
        const int r = t >> 3;
        const int s = (t & 7) ^ (r & 7);      // inverse-swizzled global col-block
        #pragma unroll
        for (int h = 0; h < 2; h++) {
            gA[h][j] = Ag + (size_t)(row0 + h * 128 + r) * K + s * 8;
            gB[h][j] = Bg + (size_t)(col0 + h * 128 + r) * K + s * 8;
        }
    }

    #define STAGE_A(tile, half, k0) do { \
        async_copy16(gA[half][0] + (k0), &SA[tile][half][tb0 * 8]); \
        async_copy16(gA[half][1] + (k0), &SA[tile][half][tb1 * 8]); } while (0)
    #define STAGE_B(tile, half, k0) do { \
        async_copy16(gB[half][0] + (k0), &SB[tile][half][tb0 * 8]); \
        async_copy16(gB[half][1] + (k0), &SB[tile][half][tb1 * 8]); } while (0)

    auto fragA = [&](int tile, int m, int kk) -> bf16x8 {
        return *(const bf16x8*)&SA[tile][wr]
            [((m * 16 + l15) << 6) + ((((kk << 2) + quad) ^ (l15 & 7)) << 3)];
    };
    auto fragB = [&](int tile, int n, int kk) -> bf16x8 {
        return *(const bf16x8*)&SB[tile][wc >> 1]
            [(((wc & 1) * 64 + n * 16 + l15) << 6) + ((((kk << 2) + quad) ^ (l15 & 7)) << 3)];
    };

    f32x4 acc[8][4];
    #pragma unroll
    for (int m = 0; m < 8; m++)
        #pragma unroll
        for (int n = 0; n < 4; n++) acc[m][n] = {0.f, 0.f, 0.f, 0.f};

    // prologue: tile0 (all 4 halves) + tile1 A-h0/B-h0.
    STAGE_A(0, 0, 0); STAGE_A(0, 1, 0);
    STAGE_B(0, 0, 0); STAGE_B(0, 1, 0);
    STAGE_A(1, 0, 64); STAGE_B(1, 0, 64);
    VMCNT(4);
    BAR();

    const int niters = K >> 7;   // 2 K-tiles (BK=64) per iteration
    bf16x8 af[4][2], bA[2][2], bB[2][2];
    for (int it = 0; it < niters; ++it) {
        const bool st = (it + 1 < niters);
        const int kc = it << 7;
        const int kn = kc + 128;

        // ---- P1
        #pragma unroll
        for (int m = 0; m < 4; m++) { af[m][0] = fragA(0, m, 0); af[m][1] = fragA(0, m, 1); }
        #pragma unroll
        for (int n = 0; n < 2; n++) { bA[n][0] = fragB(0, n, 0); bA[n][1] = fragB(0, n, 1); }
        STAGE_A(1, 1, kc + 64);
        BAR(); LGKM0();
        __builtin_amdgcn_s_setprio(1);
        #pragma unroll
        for (int m = 0; m < 4; m++)
            #pragma unroll
            for (int n = 0; n < 2; n++) {
                acc[m][n] = __builtin_amdgcn_mfma_f32_16x16x32_bf16(af[m][0], bA[n][0], acc[m][n], 0, 0, 0);
                acc[m][n] = __builtin_amdgcn_mfma_f32_16x16x32_bf16(af[m][1], bA[n][1], acc[m][n], 0, 0, 0);
            }
        __builtin_amdgcn_s_setprio(0);
        BAR();

        // ---- P2
        #pragma unroll
        for (int n = 0; n < 2; n++) { bB[n][0] = fragB(0, n + 2, 0); bB[n][1] = fragB(0, n + 2, 1); }
        STAGE_B(1, 1, kc + 64);
        BAR(); LGKM0();
        __builtin_amdgcn_s_setprio(1);
        #pragma unroll
        for (int m = 0; m < 4; m++)
            #pragma unroll
            for (int n = 0; n < 2; n++) {
                acc[m][n + 2] = __builtin_amdgcn_mfma_f32_16x16x32_bf16(af[m][0], bB[n][0], acc[m][n + 2], 0, 0, 0);
                acc[m][n + 2] = __builtin_amdgcn_mfma_f32_16x16x32_bf16(af[m][1], bB[n][1], acc[m][n + 2], 0, 0, 0);
            }
        __builtin_amdgcn_s_setprio(0);
        BAR();

        // ---- P3
        #pragma unroll
        for (int m = 0; m < 4; m++) { af[m][0] = fragA(0, m + 4, 0); af[m][1] = fragA(0, m + 4, 1); }
        if (st) STAGE_B(0, 0, kn);
        BAR(); LGKM0();
        __builtin_amdgcn_s_setprio(1);
        #pragma unroll
        for (int m = 0; m < 4; m++)
            #pragma unroll
            for (int n = 0; n < 2; n++) {
                acc[m + 4][n + 2] = __builtin_amdgcn_mfma_f32_16x16x32_bf16(af[m][0], bB[n][0], acc[m + 4][n + 2], 0, 0, 0);
                acc[m + 4][n + 2] = __builtin_amdgcn_mfma_f32_16x16x32_bf16(af[m][1], bB[n][1], acc[m + 4][n + 2], 0, 0, 0);
            }
        __builtin_amdgcn_s_setprio(0);
        BAR();

        // ---- P4
        if (st) STAGE_A(0, 0, kn);
        __builtin_amdgcn_s_setprio(1);
        #pragma unroll
        for (int m = 0; m < 4; m++)
            #pragma unroll
            for (int n = 0; n < 2; n++) {
                acc[m + 4][n] = __builtin_amdgcn_mfma_f32_16x16x32_bf16(af[m][0], bA[n][0], acc[m + 4][n], 0, 0, 0);
                acc[m + 4][n] = __builtin_amdgcn_mfma_f32_16x16x32_bf16(af[m][1], bA[n][1], acc[m + 4][n], 0, 0, 0);
            }
        __builtin_amdgcn_s_setprio(0);
        if (st) { VMCNT(4); } else { VMCNT(0); }
        BAR();

        // ---- P5
        #pragma unroll
        for (int m = 0; m < 4; m++) { af[m][0] = fragA(1, m, 0); af[m][1] = fragA(1, m, 1); }
        #pragma unroll
        for (int n = 0; n < 2; n++) { bA[n][0] = fragB(1, n, 0); bA[n][1] = fragB(1, n, 1); }
        if (st) STAGE_A(0, 1, kn);
        BAR(); LGKM0();
        __builtin_amdgcn_s_setprio(1);
        #pragma unroll
        for (int m = 0; m < 4; m++)
            #pragma unroll
            for (int n = 0; n < 2; n++) {
                acc[m][n] = __builtin_amdgcn_mfma_f32_16x16x32_bf16(af[m][0], bA[n][0], acc[m][n], 0, 0, 0);
                acc[m][n] = __builtin_amdgcn_mfma_f32_16x16x32_bf16(af[m][1], bA[n][1], acc[m][n], 0, 0, 0);
            }
        __builtin_amdgcn_s_setprio(0);
        BAR();

        // ---- P6
        #pragma unroll
        for (int n = 0; n < 2; n++) { bB[n][0] = fragB(1, n + 2, 0); bB[n][1] = fragB(1, n + 2, 1); }
        if (st) STAGE_B(0, 1, kn);
        BAR(); LGKM0();
        __builtin_amdgcn_s_setprio(1);
        #pragma unroll
        for (int m = 0; m < 4; m++)
            #pragma unroll
            for (int n = 0; n < 2; n++) {
                acc[m][n + 2] = __builtin_amdgcn_mfma_f32_16x16x32_bf16(af[m][0], bB[n][0], acc[m][n + 2], 0, 0, 0);
                acc[m][n + 2] = __builtin_amdgcn_mfma_f32_16x16x32_bf16(af[m][1], bB[n][1], acc[m][n + 2], 0, 0, 0);
            }
        __builtin_amdgcn_s_setprio(0);
        BAR();

        // ---- P7
        #pragma unroll
        for (int m = 0; m < 4; m++) { af[m][0] = fragA(1, m + 4, 0); af[m][1] = fragA(1, m + 4, 1); }
        if (st) STAGE_B(1, 0, kn + 64);
        BAR(); LGKM0();
        __builtin_amdgcn_s_setprio(1);
        #pragma unroll
        for (int m = 0; m < 4; m++)
            #pragma unroll
            for (int n = 0; n < 2; n++) {
                acc[m + 4][n + 2] = __builtin_amdgcn_mfma_f32_16x16x32_bf16(af[m][0], bB[n][0], acc[m + 4][n + 2], 0, 0, 0);
                acc[m + 4][n + 2] = __builtin_amdgcn_mfma_f32_16x16x32_bf16(af[m][1], bB[n][1], acc[m + 4][n + 2], 0, 0, 0);
            }
        __builtin_amdgcn_s_setprio(0);
        BAR();

        // ---- P8
        if (st) STAGE_A(1, 0, kn + 64);
        __builtin_amdgcn_s_setprio(1);
        #pragma unroll
        for (int m = 0; m < 4; m++)
            #pragma unroll
            for (int n = 0; n < 2; n++) {
                acc[m + 4][n] = __builtin_amdgcn_mfma_f32_16x16x32_bf16(af[m][0], bA[n][0], acc[m + 4][n], 0, 0, 0);
                acc[m + 4][n] = __builtin_amdgcn_mfma_f32_16x16x32_bf16(af[m][1], bA[n][1], acc[m + 4][n], 0, 0, 0);
            }
        __builtin_amdgcn_s_setprio(0);
        if (st) { VMCNT(4); BAR(); }
    }

    // ---------------- epilogue: s += exp2(acc - deb2) per 64-col strip
    {
        const int strip = cx * 4 + wc;
        #pragma unroll
        for (int m = 0; m < 8; m++) {
            #pragma unroll
            for (int r = 0; r < 4; r++) {
                const int lrow = wr * 128 + m * 16 + quad * 4 + r;
                const int row = row0 + lrow;
                float s = 0.f;
                #pragma unroll
                for (int n = 0; n < 4; n++) {
                    const int lcol = wc * 64 + n * 16 + l15;
                    float t = acc[m][n][r] - dc_s[lcol];          // log2e*(v - deb - CMAX)
                    t = (cm_s[lrow >> 6][lcol] != 0) ? -1.0e30f : t;
                    s += fexp2(t);
                }
                #pragma unroll
                for (int off = 1; off < 16; off <<= 1) s += __shfl_xor(s, off, 64);
                if (l15 == 0) partials[(size_t)row * NSTRIP + strip] = s;
            }
        }
    }
    #undef STAGE_A
    #undef STAGE_B
}

// ---------------------------------------------------------------- label logits (wave per row)
__global__ __launch_bounds__(256) void label_kernel(
    const __hip_bfloat16* __restrict__ xb, const __hip_bfloat16* __restrict__ sebf,
    const float* __restrict__ debias, const uint8_t* __restrict__ padcol,
    float* __restrict__ lab) {
    const int w = threadIdx.x >> 6, lane = threadIdx.x & 63;
    const int row = blockIdx.x * 4 + w;            // 0..8191
    const int b = row >> 6, s0 = row & 63;
    const int k = b * 65 + s0 + 1;
    const uint16_t* xp = (const uint16_t*)xb + (size_t)row * DIM + lane * 8;
    const uint16_t* sp = (const uint16_t*)sebf + (size_t)k * DIM + lane * 8;
    bf16x8 xv = *(const bf16x8*)xp;
    bf16x8 sv = *(const bf16x8*)sp;
    float a = 0.f;
    #pragma unroll
    for (int j = 0; j < 8; j++) a += b2f((uint16_t)xv[j]) * b2f((uint16_t)sv[j]);
    #pragma unroll
    for (int off = 32; off > 0; off >>= 1) a += __shfl_xor(a, off, 64);
    if (lane == 0)
        lab[row] = padcol[k] ? NEG_INF : (a - debias[k]);
}

// ---------------------------------------------------------------- combine + reduce
__global__ __launch_bounds__(256) void combine_kernel(
    const float* __restrict__ partials, const float* __restrict__ label_logit,
    const float* __restrict__ log_mask, float* __restrict__ bsums) {
    const int row = blockIdx.x * 256 + threadIdx.x;
    const float lab = label_logit[row];
    // label column is colmask'd in the GEMM; re-add its exp term here
    float Ls = fexp2((lab - CMAX) * LOG2E);
    const float4* pr = (const float4*)(partials + (size_t)row * NSTRIP);
    for (int t = 0; t < NSTRIP / 4; t++) {
        float4 v = pr[t];
        Ls += v.x + v.y + v.z + v.w;
    }
    const float lse = CMAX + logf(Ls);
    const float valid = (log_mask[row] != 0.0f) ? 1.0f : 0.0f;
    float a = (lse - lab) * valid;
    float c = valid;
    __shared__ float sa[4], sc_[4];
    #pragma unroll
    for (int off = 32; off > 0; off >>= 1) {
        a += __shfl_down(a, off, 64);
        c += __shfl_down(c, off, 64);
    }
    const int lane = threadIdx.x & 63, w = threadIdx.x >> 6;
    if (lane == 0) { sa[w] = a; sc_[w] = c; }
    __syncthreads();
    if (threadIdx.x == 0) {
        bsums[blockIdx.x * 2 + 0] = sa[0] + sa[1] + sa[2] + sa[3];
        bsums[blockIdx.x * 2 + 1] = sc_[0] + sc_[1] + sc_[2] + sc_[3];
    }
}

__global__ __launch_bounds__(64) void finalize_kernel(
    const float* __restrict__ bsums, float* __restrict__ out) {
    const int t = threadIdx.x;
    float a = 0.f, c = 0.f;
    if (t < 32) { a = bsums[2 * t]; c = bsums[2 * t + 1]; }
    #pragma unroll
    for (int off = 32; off > 0; off >>= 1) {
        a += __shfl_down(a, off, 64);
        c += __shfl_down(c, off, 64);
    }
    if (t == 0) out[0] = a / c;
}

// ---------------------------------------------------------------- launch
extern "C" void kernel_launch(void* const* d_in, const int* in_sizes, int n_in,
                              void* d_out, int out_size, void* d_ws, size_t ws_size,
                              hipStream_t stream) {
    const int*   ids    = (const int*)d_in[0];
    const float* lm     = (const float*)d_in[1];
    const float* emb    = (const float*)d_in[2];
    const float* pos    = (const float*)d_in[3];
    const float* qkv_w  = (const float*)d_in[4];
    const float* out_w  = (const float*)d_in[5];
    const float* ffn1_w = (const float*)d_in[6];
    const float* ffn2_w = (const float*)d_in[7];
    const float* pop    = (const float*)d_in[8];
    float* out = (float*)d_out;

    char* p = (char*)d_ws;
    auto alloc = [&](size_t bytes) {
        char* r = p;
        p += (bytes + 255) & ~(size_t)255;
        return r;
    };
    typedef __hip_bfloat16 bf16;
    bf16*    sebf     = (bf16*)alloc((size_t)NCOLP * DIM * 2);       // 8.65 MB (padded)
    float*   debias   = (float*)alloc((size_t)NCOLP * 4);
    float*   deb2     = (float*)alloc((size_t)NCOLP * 4);
    uint8_t* padcol   = (uint8_t*)alloc(NCOLP);
    uint8_t* colmask  = (uint8_t*)alloc((size_t)BSZ * NCOLP);        // 1.08 MB (padded)
    bf16*    xb       = (bf16*)alloc((size_t)NROW * DIM * 2);        // 8.4 MB (residual)
    bf16*    xbs      = (bf16*)alloc((size_t)NROW * DIM * 2);        // 8.4 MB (scaled A)
    bf16*    big      = (bf16*)alloc((size_t)NROW * 2048 * 2);       // 33.6 MB (qkv / h)
    bf16*    tmp1     = (bf16*)alloc((size_t)NROW * DIM * 2);        // attn out
    bf16*    tmp2     = (bf16*)alloc((size_t)NROW * DIM * 2);        // proj / f2
    float*   partials = (float*)alloc((size_t)NROW * NSTRIP * 4);    // 4.3 MB
    float*   lab      = (float*)alloc((size_t)NROW * 4);
    float*   bsums    = (float*)alloc(64 * 4);
    bf16*    qkvT     = (bf16*)alloc((size_t)NLAYER * 1536 * 512 * 2);
    bf16*    outT     = (bf16*)alloc((size_t)NLAYER * 512 * 512 * 2);
    bf16*    f1T      = (bf16*)alloc((size_t)NLAYER * 2048 * 512 * 2);
    bf16*    f2T      = (bf16*)alloc((size_t)NLAYER * 512 * 2048 * 2);

    transpose_bf16_kernel<<<dim3(1536 / 32, 512 / 32, NLAYER), 256, 0, stream>>>(
        qkv_w, qkvT, 512, 1536);
    transpose_bf16_kernel<<<dim3(512 / 32, 512 / 32, NLAYER), 256, 0, stream>>>(
        out_w, outT, 512, 512);
    transpose_bf16_kernel<<<dim3(2048 / 32, 512 / 32, NLAYER), 256, 0, stream>>>(
        ffn1_w, f1T, 512, 2048);
    transpose_bf16_kernel<<<dim3(512 / 32, 2048 / 32, NLAYER), 256, 0, stream>>>(
        ffn2_w, f2T, 2048, 512);

    gather_posln_kernel<<<NCOL / 4, 256, 0, stream>>>(ids, emb, pop, pos, sebf, debias, deb2, xb);
    mask_kernel<<<BSZ * 8, 256, 0, stream>>>(ids, lm, colmask, padcol);

    for (int l = 0; l < NLAYER; l++) {
        gemm_bt_kernel<128, false><<<(1536 / 128) * 64, 256, 0, stream>>>(
            xb, qkvT + (size_t)l * 1536 * 512, big, 1536, 512);
        attn_mfma_kernel<<<BSZ * HEADS, 256, 0, stream>>>(big, lm, tmp1);
        gemm_bt_kernel<64, false><<<(512 / 64) * 64, 256, 0, stream>>>(
            tmp1, outT + (size_t)l * 512 * 512, tmp2, 512, 512);
        resid_ln_kernel<false><<<NROW / 4, 256, 0, stream>>>(xb, tmp2, nullptr);
        gemm_bt_kernel<128, true><<<(2048 / 128) * 64, 256, 0, stream>>>(
            xb, f1T + (size_t)l * 2048 * 512, big, 2048, 512);
        gemm_bt_kernel<64, false><<<(512 / 64) * 64, 256, 0, stream>>>(
            big, f2T + (size_t)l * 512 * 2048, tmp2, 512, 2048);
        if (l == NLAYER - 1)
            resid_ln_kernel<true><<<NROW / 4, 256, 0, stream>>>(xb, tmp2, xbs);
        else
            resid_ln_kernel<false><<<NROW / 4, 256, 0, stream>>>(xb, tmp2, nullptr);
    }

    label_kernel<<<NROW / 4, 256, 0, stream>>>(xb, sebf, debias, padcol, lab);
    gemm256_logits_kernel<<<32 * (NCOLP / 256), 512, 0, stream>>>(
        xbs, sebf, NCOLP, 512, deb2, colmask, partials);
    combine_kernel<<<NROW / 256, 256, 0, stream>>>(partials, lab, lm, bsums);
    finalize_kernel<<<1, 64, 0, stream>>>(bsums, out);
}

// Round 5
// 625.587 us; speedup vs baseline: 1.1634x; 1.0041x over previous
//
#include <hip/hip_runtime.h>
#include <hip/hip_bf16.h>
#include <cstdint>
#include <cstddef>

#define NEG_INF -10000.0f

constexpr int BSZ  = 128;
constexpr int SEQ  = 64;     // L
constexpr int DIM  = 512;    // D
constexpr int HEADS = 8;
constexpr int NLAYER = 2;
constexpr int NCOL = BSZ * (SEQ + 1);   // 8320
constexpr int NCOLP = 8448;             // padded to 33*256 for 256-wide tiles
constexpr int NROW = BSZ * SEQ;         // 8192
constexpr int NSTRIP = NCOLP / 64;      // 132
constexpr float CMAX = 40.0f;           // analytic upper bound (max logit < 28)
constexpr float LOG2E = 1.4426950408889634f;

typedef __attribute__((ext_vector_type(8))) short bf16x8;   // 8 bf16 in 4 VGPRs
typedef __attribute__((ext_vector_type(4))) float f32x4;

// async global->LDS, 16B per lane, dest = ldsbase + lane*16
__device__ __forceinline__ void async_copy16(const void* g, void* l) {
    __builtin_amdgcn_global_load_lds(
        (const __attribute__((address_space(1))) void*)g,
        (__attribute__((address_space(3))) void*)l, 16, 0, 0);
}

__device__ __forceinline__ float b2f(uint16_t u) {
    return __builtin_bit_cast(float, (uint32_t)u << 16);
}
__device__ __forceinline__ uint16_t f2b(float f) {
    __hip_bfloat16 h = __float2bfloat16(f);
    return __builtin_bit_cast(uint16_t, h);
}

// raw v_exp_f32 (exp2) — single instruction, no libm guards
__device__ __forceinline__ float fexp2(float x) {
    float r; asm("v_exp_f32 %0, %1" : "=v"(r) : "v"(x)); return r;
}

// fast tanh-gelu: tanh(u) = 1 - 2/(e^{2u}+1), e^{2u} = exp2(2u*log2e)
__device__ __forceinline__ float gelu_f(float v) {
    float u = 0.7978845608028654f * (v + 0.044715f * v * v * v);
    float t2 = fexp2(u * (2.0f * LOG2E));
    float th = 1.0f - 2.0f * __builtin_amdgcn_rcpf(t2 + 1.0f);
    return 0.5f * v * (1.0f + th);
}

// XCD-aware swizzle for the 128-tile GEMM (64 row-blocks of 128 rows).
__device__ __forceinline__ void swizzle_rc(int id, int& ry, int& cx) {
    ry = (id & 7) * 8 + ((id >> 3) & 7);
    cx = id >> 6;
}

#define BAR() __builtin_amdgcn_s_barrier()
#define LGKM0() asm volatile("s_waitcnt lgkmcnt(0)" ::: "memory")
#define VMCNT(n) asm volatile("s_waitcnt vmcnt(" #n ")" ::: "memory")

// ---------------------------------------------------------------- gather + pos + LN (wave per row)
__global__ __launch_bounds__(256) void gather_posln_kernel(
    const int* __restrict__ ids, const float* __restrict__ table,
    const float* __restrict__ pop, const float* __restrict__ pos,
    __hip_bfloat16* __restrict__ sebf, float* __restrict__ debias,
    float* __restrict__ deb2, __hip_bfloat16* __restrict__ xb) {
    const int w = threadIdx.x >> 6, lane = threadIdx.x & 63;
    const int k = blockIdx.x * 4 + w;              // 0..8319
    const int b = k / 65, s = k - b * 65;
    const int id = ids[k];
    const float* src = table + (size_t)id * DIM + lane * 8;
    float4 u0 = *(const float4*)src;
    float4 u1 = *(const float4*)(src + 4);
    float v[8] = {u0.x, u0.y, u0.z, u0.w, u1.x, u1.y, u1.z, u1.w};
    bf16x8 se;
    #pragma unroll
    for (int j = 0; j < 8; j++) se[j] = (short)f2b(v[j]);
    *(bf16x8*)((uint16_t*)sebf + (size_t)k * DIM + lane * 8) = se;
    if (lane == 0) {
        const float lp = logf(pop[id]);
        debias[k] = lp;
        deb2[k] = (lp + CMAX) * LOG2E;
    }
    if (s < 64) {
        const float* pp = pos + (size_t)s * DIM + lane * 8;
        float4 p0 = *(const float4*)pp;
        float4 p1 = *(const float4*)(pp + 4);
        float t[8] = {v[0] + p0.x, v[1] + p0.y, v[2] + p0.z, v[3] + p0.w,
                      v[4] + p1.x, v[5] + p1.y, v[6] + p1.z, v[7] + p1.w};
        float sum = 0.f, sq = 0.f;
        #pragma unroll
        for (int j = 0; j < 8; j++) { sum += t[j]; sq += t[j] * t[j]; }
        #pragma unroll
        for (int off = 32; off > 0; off >>= 1) {
            sum += __shfl_xor(sum, off, 64);
            sq  += __shfl_xor(sq,  off, 64);
        }
        const float mean = sum * (1.0f / 512.0f);
        const float var  = sq * (1.0f / 512.0f) - mean * mean;
        const float rs = rsqrtf(var + 1e-5f);
        bf16x8 o;
        #pragma unroll
        for (int j = 0; j < 8; j++) o[j] = (short)f2b((t[j] - mean) * rs);
        *(bf16x8*)((uint16_t*)xb + (size_t)(b * 64 + s) * DIM + lane * 8) = o;
    }
}

// ---------------------------------------------------------------- masks (padded to NCOLP)
__global__ __launch_bounds__(256) void mask_kernel(
    const int* __restrict__ ids, const float* __restrict__ log_mask,
    uint8_t* __restrict__ colmask, uint8_t* __restrict__ padcol) {
    const int bi = blockIdx.x >> 3, seg = blockIdx.x & 7;
    __shared__ int sid[65];
    if (threadIdx.x < 65) sid[threadIdx.x] = ids[bi * 65 + threadIdx.x];
    __syncthreads();
    const int kend = (seg + 1) * (NCOLP / 8);
    for (int k = seg * (NCOLP / 8) + threadIdx.x; k < kend; k += 256) {
        uint8_t cmv, pcv;
        if (k < NCOL) {
            const int id = ids[k];
            bool mem = false;
            #pragma unroll
            for (int j = 0; j < 65; j++) mem |= (sid[j] == id);
            const int i2 = k / 65, jj = k - i2 * 65;
            const bool pc = (jj < 64) && (log_mask[i2 * 64 + jj] == 0.0f);
            cmv = (mem || pc) ? 1 : 0;
            pcv = pc ? 1 : 0;
        } else { cmv = 1; pcv = 1; }   // padded columns always masked
        colmask[(size_t)bi * NCOLP + k] = cmv;
        if (bi == 0) padcol[k] = pcv;
    }
}

// ---------------------------------------------------------------- weight transpose+cast
__global__ __launch_bounds__(256) void transpose_bf16_kernel(
    const float* __restrict__ W, __hip_bfloat16* __restrict__ WT, int K, int N) {
    __shared__ float tile[32][33];
    const size_t loff = (size_t)blockIdx.z * K * N;
    const int nt = blockIdx.x * 32, kt = blockIdx.y * 32;
    const int c = threadIdx.x & 31, r = threadIdx.x >> 5;
    #pragma unroll
    for (int p = 0; p < 4; p++)
        tile[p * 8 + r][c] = W[loff + (size_t)(kt + p * 8 + r) * N + nt + c];
    __syncthreads();
    #pragma unroll
    for (int p = 0; p < 4; p++)
        WT[loff + (size_t)(nt + p * 8 + r) * K + kt + c] = __float2bfloat16(tile[c][p * 8 + r]);
}

// ---------------------------------------------------------------- residual + LN (wave per row, bf16)
// SCALED: also write LN(x)*log2e to xs (A-matrix for the exp2-folded logits GEMM)
template<bool SCALED>
__global__ __launch_bounds__(256) void resid_ln_kernel(
    __hip_bfloat16* __restrict__ xb, const __hip_bfloat16* __restrict__ y,
    __hip_bfloat16* __restrict__ xs) {
    const int w = threadIdx.x >> 6, lane = threadIdx.x & 63;
    const int row = blockIdx.x * 4 + w;
    uint16_t* xp = (uint16_t*)xb + (size_t)row * DIM + lane * 8;
    const uint16_t* yp = (const uint16_t*)y + (size_t)row * DIM + lane * 8;
    bf16x8 xv = *(const bf16x8*)xp;
    bf16x8 yv = *(const bf16x8*)yp;
    float t[8];
    float sum = 0.f, sq = 0.f;
    #pragma unroll
    for (int j = 0; j < 8; j++) {
        t[j] = b2f((uint16_t)xv[j]) + b2f((uint16_t)yv[j]);
        sum += t[j]; sq += t[j] * t[j];
    }
    #pragma unroll
    for (int off = 32; off > 0; off >>= 1) {
        sum += __shfl_xor(sum, off, 64);
        sq  += __shfl_xor(sq,  off, 64);
    }
    const float mean = sum * (1.0f / 512.0f);
    const float var  = sq * (1.0f / 512.0f) - mean * mean;
    const float rs = rsqrtf(var + 1e-5f);
    bf16x8 o;
    #pragma unroll
    for (int j = 0; j < 8; j++) o[j] = (short)f2b((t[j] - mean) * rs);
    *(bf16x8*)xp = o;
    if (SCALED) {
        bf16x8 os;
        #pragma unroll
        for (int j = 0; j < 8; j++) os[j] = (short)f2b((t[j] - mean) * rs * LOG2E);
        *(bf16x8*)((uint16_t*)xs + (size_t)row * DIM + lane * 8) = os;
    }
}

// ---------------------------------------------------------------- bf16 MFMA GEMM v2 (B^T), BK=32
// T2+T4 on the 128xTN tile: cross-iter dbuf, 2-deep counted-vmcnt prefetch (no
// mid-loop vmcnt(0) drain), XOR-swizzled LDS (linear async dest, inverse-swizzled
// global source, swizzled reads -> 2-way max bank aliasing = free).
template<int TN, bool GELU>
__global__ __launch_bounds__(256) void gemm_bt2_kernel(
    const __hip_bfloat16* __restrict__ A, const __hip_bfloat16* __restrict__ Bt,
    __hip_bfloat16* __restrict__ C, int N, int K) {
    constexpr int AI = (TN == 128) ? 4 : 2;
    __shared__ uint16_t As[2][128 * 32];
    __shared__ uint16_t Bs[2][TN * 32];
    const int tid = threadIdx.x, w = tid >> 6, lane = tid & 63;
    const int quad = lane >> 4, l15 = lane & 15;
    const int wr = (TN == 128) ? (w >> 1) : w;
    const int wc = (TN == 128) ? (w & 1) : 0;
    const int rowbase = wr * (AI * 16);
    int ry, cx;
    swizzle_rc(blockIdx.x, ry, cx);
    const int row0 = ry * 128, col0 = cx * TN;
    const uint16_t* Ag = (const uint16_t*)A;
    const uint16_t* Bg = (const uint16_t*)Bt;

    // staging: LDS dest linear (lane*16); source k-slot inverse-swizzled.
    // LDS[r][slot] holds global slot ^ ((r>>1)&3); (r>>1)&3 == (lane>>3)&3.
    const int srow = lane >> 2;
    const int ssl = ((lane & 3) ^ ((lane >> 3) & 3)) * 8;
    const uint16_t* sA0 = Ag + (size_t)(row0 + w * 16 + srow) * K + ssl;
    const uint16_t* sA1 = sA0 + (size_t)64 * K;
    const uint16_t* sB0 = Bg + (size_t)(col0 + w * 16 + srow) * K + ssl;
    const uint16_t* sB1 = sB0 + (size_t)64 * K;   // unused for TN==64

    auto STAGE = [&](int buf, int kk) {
        async_copy16(sA0 + kk, &As[buf][w * 512]);
        async_copy16(sA1 + kk, &As[buf][2048 + w * 512]);
        async_copy16(sB0 + kk, &Bs[buf][w * 512]);
        if (TN == 128) async_copy16(sB1 + kk, &Bs[buf][2048 + w * 512]);
    };

    f32x4 acc[AI][4];
    #pragma unroll
    for (int i = 0; i < AI; i++)
        #pragma unroll
        for (int j = 0; j < 4; j++) acc[i][j] = {0.f, 0.f, 0.f, 0.f};

    // prologue: tiles 0 and 1 in flight; gate tile 0.
    STAGE(0, 0); STAGE(1, 32);
    if (TN == 128) { VMCNT(4); } else { VMCNT(3); }
    BAR();

    const int NT = K >> 5;
    const int swz = (quad ^ ((l15 >> 1) & 3)) * 8;   // read-side swizzle (elems)
    for (int t = 0; t < NT; ++t) {
        const int buf = t & 1;
        bf16x8 af[AI], bfr[4];
        #pragma unroll
        for (int i = 0; i < AI; i++)
            af[i] = *(const bf16x8*)&As[buf][(rowbase + i * 16 + l15) * 32 + swz];
        #pragma unroll
        for (int j = 0; j < 4; j++)
            bfr[j] = *(const bf16x8*)&Bs[buf][(wc * 64 + j * 16 + l15) * 32 + swz];
        LGKM0();
        __builtin_amdgcn_sched_barrier(0);
        BAR();                               // all waves done reading buf -> reusable
        if (t + 2 < NT) STAGE(buf, (t + 2) * 32);
        __builtin_amdgcn_s_setprio(1);
        #pragma unroll
        for (int i = 0; i < AI; i++)
            #pragma unroll
            for (int j = 0; j < 4; j++)
                acc[i][j] = __builtin_amdgcn_mfma_f32_16x16x32_bf16(af[i], bfr[j], acc[i][j], 0, 0, 0);
        __builtin_amdgcn_s_setprio(0);
        // gate: tile t+1 landed (tile t+2 still in flight)
        if (t + 2 < NT) { if (TN == 128) { VMCNT(4); } else { VMCNT(3); } }
        else if (t + 1 < NT) { VMCNT(0); }
        BAR();
    }

    #pragma unroll
    for (int i = 0; i < AI; i++) {
        #pragma unroll
        for (int r = 0; r < 4; r++) {
            const int row = row0 + rowbase + i * 16 + quad * 4 + r;
            #pragma unroll
            for (int j = 0; j < 4; j++) {
                const int col = col0 + wc * 64 + j * 16 + l15;
                float v = acc[i][j][r];
                if (GELU) v = gelu_f(v);
                C[(size_t)row * N + col] = __float2bfloat16(v);
            }
        }
    }
}

// ---------------------------------------------------------------- MFMA attention (per b,h)
__global__ __launch_bounds__(256) void attn_mfma_kernel(
    const __hip_bfloat16* __restrict__ qkv, const float* __restrict__ log_mask,
    __hip_bfloat16* __restrict__ obuf) {
    constexpr int QS = 72;    // Q/K/P LDS row stride (uint16)
    constexpr int VS32 = 36;  // V^T LDS row stride (uint32 pairs)
    __shared__ uint16_t Qs[64 * QS];
    __shared__ uint16_t Ks_[64 * QS];
    __shared__ uint16_t Ps[64 * QS];
    __shared__ uint32_t Vt32[64 * VS32];   // Vt32[d][sp] = (V[2sp][d], V[2sp+1][d])
    __shared__ float mask_s[64];
    const int b = blockIdx.x >> 3, h = blockIdx.x & 7;
    const int tid = threadIdx.x, w = tid >> 6, lane = tid & 63;
    const int quad = lane >> 4, l15 = lane & 15;
    const uint16_t* qg = (const uint16_t*)qkv;

    if (tid < 64) mask_s[tid] = log_mask[b * 64 + tid];
    // stage Q,K row-major
    #pragma unroll
    for (int it = 0; it < 2; it++) {
        const int idx = it * 256 + tid;          // 0..511
        const int s = idx >> 3, c = (idx & 7) * 8;
        const size_t gbase = (size_t)(b * 64 + s) * 1536 + h * 64 + c;
        *(bf16x8*)&Qs[s * QS + c]  = *(const bf16x8*)&qg[gbase];
        *(bf16x8*)&Ks_[s * QS + c] = *(const bf16x8*)&qg[gbase + 512];
    }
    // stage V transposed, two rows packed per 32-bit word
    {
        const int sp = tid >> 3;                 // 0..31
        const int c = (tid & 7) * 8;
        const size_t gbase = (size_t)(b * 64 + sp * 2) * 1536 + 1024 + h * 64 + c;
        bf16x8 v0 = *(const bf16x8*)&qg[gbase];
        bf16x8 v1 = *(const bf16x8*)&qg[gbase + 1536];
        #pragma unroll
        for (int jj = 0; jj < 8; jj++)
            Vt32[(c + jj) * VS32 + sp] =
                (uint32_t)(uint16_t)v0[jj] | ((uint32_t)(uint16_t)v1[jj] << 16);
    }
    __syncthreads();

    // ---- S = Q K^T for rows w*16..w*16+15
    f32x4 sacc[4];
    #pragma unroll
    for (int j = 0; j < 4; j++) sacc[j] = {0.f, 0.f, 0.f, 0.f};
    #pragma unroll
    for (int k0 = 0; k0 < 2; k0++) {
        bf16x8 aq = *(const bf16x8*)&Qs[(w * 16 + l15) * QS + k0 * 32 + quad * 8];
        #pragma unroll
        for (int j = 0; j < 4; j++) {
            bf16x8 bk = *(const bf16x8*)&Ks_[(j * 16 + l15) * QS + k0 * 32 + quad * 8];
            sacc[j] = __builtin_amdgcn_mfma_f32_16x16x32_bf16(aq, bk, sacc[j], 0, 0, 0);
        }
    }
    // ---- softmax per row; P -> LDS bf16
    #pragma unroll
    for (int r = 0; r < 4; r++) {
        const int q = w * 16 + quad * 4 + r;
        float vals[4];
        float vmax = -3.0e38f;
        #pragma unroll
        for (int j = 0; j < 4; j++) {
            const int col = j * 16 + l15;
            const bool ok = (col <= q) && (mask_s[col] != 0.0f);
            float v = sacc[j][r] * 0.125f + (ok ? 0.0f : NEG_INF);
            vals[j] = v;
            vmax = fmaxf(vmax, v);
        }
        #pragma unroll
        for (int off = 1; off < 16; off <<= 1) vmax = fmaxf(vmax, __shfl_xor(vmax, off, 64));
        float e[4], s = 0.f;
        #pragma unroll
        for (int j = 0; j < 4; j++) { e[j] = fexp2((vals[j] - vmax) * LOG2E); s += e[j]; }
        #pragma unroll
        for (int off = 1; off < 16; off <<= 1) s += __shfl_xor(s, off, 64);
        const float inv = 1.0f / s;
        #pragma unroll
        for (int j = 0; j < 4; j++)
            Ps[q * QS + j * 16 + l15] = f2b(e[j] * inv);
    }
    __syncthreads();

    // ---- O = P V : B-frags contiguous b128 from Vt32
    f32x4 oacc[4];
    #pragma unroll
    for (int j = 0; j < 4; j++) oacc[j] = {0.f, 0.f, 0.f, 0.f};
    #pragma unroll
    for (int k0 = 0; k0 < 2; k0++) {
        bf16x8 ap = *(const bf16x8*)&Ps[(w * 16 + l15) * QS + k0 * 32 + quad * 8];
        #pragma unroll
        for (int j = 0; j < 4; j++) {
            bf16x8 bv = *(const bf16x8*)&Vt32[(j * 16 + l15) * VS32 + k0 * 16 + quad * 4];
            oacc[j] = __builtin_amdgcn_mfma_f32_16x16x32_bf16(ap, bv, oacc[j], 0, 0, 0);
        }
    }
    #pragma unroll
    for (int r = 0; r < 4; r++) {
        const int q = w * 16 + quad * 4 + r;
        #pragma unroll
        for (int j = 0; j < 4; j++) {
            const int d = j * 16 + l15;
            obuf[(size_t)(b * 64 + q) * 512 + h * 64 + d] = __float2bfloat16(oacc[j][r]);
        }
    }
}

// ---------------------------------------------------------------- 256x256 8-wave 8-phase logits GEMM
// A pre-scaled by log2e; deb2 pre-folded; epilogue = sub + cndmask + v_exp_f32 + add.
__global__ __launch_bounds__(512) void gemm256_logits_kernel(
    const __hip_bfloat16* __restrict__ A, const __hip_bfloat16* __restrict__ Bt,
    int N, int K,
    const float* __restrict__ deb2, const uint8_t* __restrict__ colmask,
    float* __restrict__ partials) {
    __shared__ uint16_t SA[2][2][128 * 64];   // [ktile-slot][half][row*64 + swz-col]
    __shared__ uint16_t SB[2][2][128 * 64];
    __shared__ float dc_s[256];
    __shared__ uint8_t cm_s[4][256];

    const int tid = threadIdx.x;
    const int w = tid >> 6, lane = tid & 63;
    const int quad = lane >> 4, l15 = lane & 15;
    const int wr = w >> 2, wc = w & 3;        // 2(M) x 4(N) wave grid, wave = 128x64

    const int nwg = gridDim.x;
    const int xid = (blockIdx.x & 7) * (nwg >> 3) + (blockIdx.x >> 3);  // XCD swizzle
    const int ry = xid & 31, cx = xid >> 5;
    const int row0 = ry * 256, col0 = cx * 256;

    const uint16_t* Ag = (const uint16_t*)A;
    const uint16_t* Bg = (const uint16_t*)Bt;

    if (tid < 256) dc_s[tid] = deb2[col0 + tid];
    #pragma unroll
    for (int j = 0; j < 2; j++) {
        const int e = j * 512 + tid;
        cm_s[e >> 8][e & 255] =
            colmask[(size_t)((row0 >> 6) + (e >> 8)) * NCOLP + col0 + (e & 255)];
    }

    // per-lane swizzled staging source pointers; LDS dest stays linear
    const int tb0 = w << 6, tb1 = 512 + (w << 6);
    const uint16_t* gA[2][2];
    const uint16_t* gB[2][2];
    #pragma unroll
    for (int j = 0; j < 2; j++) {
        const int t = j * 512 + (w << 6) + lane;
        const int r = t >> 3;
        const int s = (t & 7) ^ (r & 7);      // inverse-swizzled global col-block
        #pragma unroll
        for (int h = 0; h < 2; h++) {
            gA[h][j] = Ag + (size_t)(row0 + h * 128 + r) * K + s * 8;
            gB[h][j] = Bg + (size_t)(col0 + h * 128 + r) * K + s * 8;
        }
    }

    #define STAGE_A(tile, half, k0) do { \
        async_copy16(gA[half][0] + (k0), &SA[tile][half][tb0 * 8]); \
        async_copy16(gA[half][1] + (k0), &SA[tile][half][tb1 * 8]); } while (0)
    #define STAGE_B(tile, half, k0) do { \
        async_copy16(gB[half][0] + (k0), &SB[tile][half][tb0 * 8]); \
        async_copy16(gB[half][1] + (k0), &SB[tile][half][tb1 * 8]); } while (0)

    auto fragA = [&](int tile, int m, int kk) -> bf16x8 {
        return *(const bf16x8*)&SA[tile][wr]
            [((m * 16 + l15) << 6) + ((((kk << 2) + quad) ^ (l15 & 7)) << 3)];
    };
    auto fragB = [&](int tile, int n, int kk) -> bf16x8 {
        return *(const bf16x8*)&SB[tile][wc >> 1]
            [(((wc & 1) * 64 + n * 16 + l15) << 6) + ((((kk << 2) + quad) ^ (l15 & 7)) << 3)];
    };

    f32x4 acc[8][4];
    #pragma unroll
    for (int m = 0; m < 8; m++)
        #pragma unroll
        for (int n = 0; n < 4; n++) acc[m][n] = {0.f, 0.f, 0.f, 0.f};

    // prologue: tile0 (all 4 halves) + tile1 A-h0/B-h0.
    STAGE_A(0, 0, 0); STAGE_A(0, 1, 0);
    STAGE_B(0, 0, 0); STAGE_B(0, 1, 0);
    STAGE_A(1, 0, 64); STAGE_B(1, 0, 64);
    VMCNT(4);
    BAR();

    const int niters = K >> 7;   // 2 K-tiles (BK=64) per iteration
    bf16x8 af[4][2], bA[2][2], bB[2][2];
    for (int it = 0; it < niters; ++it) {
        const bool st = (it + 1 < niters);
        const int kc = it << 7;
        const int kn = kc + 128;

        // ---- P1
        #pragma unroll
        for (int m = 0; m < 4; m++) { af[m][0] = fragA(0, m, 0); af[m][1] = fragA(0, m, 1); }
        #pragma unroll
        for (int n = 0; n < 2; n++) { bA[n][0] = fragB(0, n, 0); bA[n][1] = fragB(0, n, 1); }
        STAGE_A(1, 1, kc + 64);
        BAR(); LGKM0();
        __builtin_amdgcn_s_setprio(1);
        #pragma unroll
        for (int m = 0; m < 4; m++)
            #pragma unroll
            for (int n = 0; n < 2; n++) {
                acc[m][n] = __builtin_amdgcn_mfma_f32_16x16x32_bf16(af[m][0], bA[n][0], acc[m][n], 0, 0, 0);
                acc[m][n] = __builtin_amdgcn_mfma_f32_16x16x32_bf16(af[m][1], bA[n][1], acc[m][n], 0, 0, 0);
            }
        __builtin_amdgcn_s_setprio(0);
        BAR();

        // ---- P2
        #pragma unroll
        for (int n = 0; n < 2; n++) { bB[n][0] = fragB(0, n + 2, 0); bB[n][1] = fragB(0, n + 2, 1); }
        STAGE_B(1, 1, kc + 64);
        BAR(); LGKM0();
        __builtin_amdgcn_s_setprio(1);
        #pragma unroll
        for (int m = 0; m < 4; m++)
            #pragma unroll
            for (int n = 0; n < 2; n++) {
                acc[m][n + 2] = __builtin_amdgcn_mfma_f32_16x16x32_bf16(af[m][0], bB[n][0], acc[m][n + 2], 0, 0, 0);
                acc[m][n + 2] = __builtin_amdgcn_mfma_f32_16x16x32_bf16(af[m][1], bB[n][1], acc[m][n + 2], 0, 0, 0);
            }
        __builtin_amdgcn_s_setprio(0);
        BAR();

        // ---- P3
        #pragma unroll
        for (int m = 0; m < 4; m++) { af[m][0] = fragA(0, m + 4, 0); af[m][1] = fragA(0, m + 4, 1); }
        if (st) STAGE_B(0, 0, kn);
        BAR(); LGKM0();
        __builtin_amdgcn_s_setprio(1);
        #pragma unroll
        for (int m = 0; m < 4; m++)
            #pragma unroll
            for (int n = 0; n < 2; n++) {
                acc[m + 4][n + 2] = __builtin_amdgcn_mfma_f32_16x16x32_bf16(af[m][0], bB[n][0], acc[m + 4][n + 2], 0, 0, 0);
                acc[m + 4][n + 2] = __builtin_amdgcn_mfma_f32_16x16x32_bf16(af[m][1], bB[n][1], acc[m + 4][n + 2], 0, 0, 0);
            }
        __builtin_amdgcn_s_setprio(0);
        BAR();

        // ---- P4
        if (st) STAGE_A(0, 0, kn);
        __builtin_amdgcn_s_setprio(1);
        #pragma unroll
        for (int m = 0; m < 4; m++)
            #pragma unroll
            for (int n = 0; n < 2; n++) {
                acc[m + 4][n] = __builtin_amdgcn_mfma_f32_16x16x32_bf16(af[m][0], bA[n][0], acc[m + 4][n], 0, 0, 0);
                acc[m + 4][n] = __builtin_amdgcn_mfma_f32_16x16x32_bf16(af[m][1], bA[n][1], acc[m + 4][n], 0, 0, 0);
            }
        __builtin_amdgcn_s_setprio(0);
        if (st) { VMCNT(4); } else { VMCNT(0); }
        BAR();

        // ---- P5
        #pragma unroll
        for (int m = 0; m < 4; m++) { af[m][0] = fragA(1, m, 0); af[m][1] = fragA(1, m, 1); }
        #pragma unroll
        for (int n = 0; n < 2; n++) { bA[n][0] = fragB(1, n, 0); bA[n][1] = fragB(1, n, 1); }
        if (st) STAGE_A(0, 1, kn);
        BAR(); LGKM0();
        __builtin_amdgcn_s_setprio(1);
        #pragma unroll
        for (int m = 0; m < 4; m++)
            #pragma unroll
            for (int n = 0; n < 2; n++) {
                acc[m][n] = __builtin_amdgcn_mfma_f32_16x16x32_bf16(af[m][0], bA[n][0], acc[m][n], 0, 0, 0);
                acc[m][n] = __builtin_amdgcn_mfma_f32_16x16x32_bf16(af[m][1], bA[n][1], acc[m][n], 0, 0, 0);
            }
        __builtin_amdgcn_s_setprio(0);
        BAR();

        // ---- P6
        #pragma unroll
        for (int n = 0; n < 2; n++) { bB[n][0] = fragB(1, n + 2, 0); bB[n][1] = fragB(1, n + 2, 1); }
        if (st) STAGE_B(0, 1, kn);
        BAR(); LGKM0();
        __builtin_amdgcn_s_setprio(1);
        #pragma unroll
        for (int m = 0; m < 4; m++)
            #pragma unroll
            for (int n = 0; n < 2; n++) {
                acc[m][n + 2] = __builtin_amdgcn_mfma_f32_16x16x32_bf16(af[m][0], bB[n][0], acc[m][n + 2], 0, 0, 0);
                acc[m][n + 2] = __builtin_amdgcn_mfma_f32_16x16x32_bf16(af[m][1], bB[n][1], acc[m][n + 2], 0, 0, 0);
            }
        __builtin_amdgcn_s_setprio(0);
        BAR();

        // ---- P7
        #pragma unroll
        for (int m = 0; m < 4; m++) { af[m][0] = fragA(1, m + 4, 0); af[m][1] = fragA(1, m + 4, 1); }
        if (st) STAGE_B(1, 0, kn + 64);
        BAR(); LGKM0();
        __builtin_amdgcn_s_setprio(1);
        #pragma unroll
        for (int m = 0; m < 4; m++)
            #pragma unroll
            for (int n = 0; n < 2; n++) {
                acc[m + 4][n + 2] = __builtin_amdgcn_mfma_f32_16x16x32_bf16(af[m][0], bB[n][0], acc[m + 4][n + 2], 0, 0, 0);
                acc[m + 4][n + 2] = __builtin_amdgcn_mfma_f32_16x16x32_bf16(af[m][1], bB[n][1], acc[m + 4][n + 2], 0, 0, 0);
            }
        __builtin_amdgcn_s_setprio(0);
        BAR();

        // ---- P8
        if (st) STAGE_A(1, 0, kn + 64);
        __builtin_amdgcn_s_setprio(1);
        #pragma unroll
        for (int m = 0; m < 4; m++)
            #pragma unroll
            for (int n = 0; n < 2; n++) {
                acc[m + 4][n] = __builtin_amdgcn_mfma_f32_16x16x32_bf16(af[m][0], bA[n][0], acc[m + 4][n], 0, 0, 0);
                acc[m + 4][n] = __builtin_amdgcn_mfma_f32_16x16x32_bf16(af[m][1], bA[n][1], acc[m + 4][n], 0, 0, 0);
            }
        __builtin_amdgcn_s_setprio(0);
        if (st) { VMCNT(4); BAR(); }
    }

    // ---------------- epilogue: s += exp2(acc - deb2) per 64-col strip
    {
        const int strip = cx * 4 + wc;
        #pragma unroll
        for (int m = 0; m < 8; m++) {
            #pragma unroll
            for (int r = 0; r < 4; r++) {
                const int lrow = wr * 128 + m * 16 + quad * 4 + r;
                const int row = row0 + lrow;
                float s = 0.f;
                #pragma unroll
                for (int n = 0; n < 4; n++) {
                    const int lcol = wc * 64 + n * 16 + l15;
                    float t = acc[m][n][r] - dc_s[lcol];          // log2e*(v - deb - CMAX)
                    t = (cm_s[lrow >> 6][lcol] != 0) ? -1.0e30f : t;
                    s += fexp2(t);
                }
                #pragma unroll
                for (int off = 1; off < 16; off <<= 1) s += __shfl_xor(s, off, 64);
                if (l15 == 0) partials[(size_t)row * NSTRIP + strip] = s;
            }
        }
    }
    #undef STAGE_A
    #undef STAGE_B
}

// ---------------------------------------------------------------- label logits (wave per row)
__global__ __launch_bounds__(256) void label_kernel(
    const __hip_bfloat16* __restrict__ xb, const __hip_bfloat16* __restrict__ sebf,
    const float* __restrict__ debias, const uint8_t* __restrict__ padcol,
    float* __restrict__ lab) {
    const int w = threadIdx.x >> 6, lane = threadIdx.x & 63;
    const int row = blockIdx.x * 4 + w;            // 0..8191
    const int b = row >> 6, s0 = row & 63;
    const int k = b * 65 + s0 + 1;
    const uint16_t* xp = (const uint16_t*)xb + (size_t)row * DIM + lane * 8;
    const uint16_t* sp = (const uint16_t*)sebf + (size_t)k * DIM + lane * 8;
    bf16x8 xv = *(const bf16x8*)xp;
    bf16x8 sv = *(const bf16x8*)sp;
    float a = 0.f;
    #pragma unroll
    for (int j = 0; j < 8; j++) a += b2f((uint16_t)xv[j]) * b2f((uint16_t)sv[j]);
    #pragma unroll
    for (int off = 32; off > 0; off >>= 1) a += __shfl_xor(a, off, 64);
    if (lane == 0)
        lab[row] = padcol[k] ? NEG_INF : (a - debias[k]);
}

// ---------------------------------------------------------------- combine + reduce
__global__ __launch_bounds__(256) void combine_kernel(
    const float* __restrict__ partials, const float* __restrict__ label_logit,
    const float* __restrict__ log_mask, float* __restrict__ bsums) {
    const int row = blockIdx.x * 256 + threadIdx.x;
    const float lab = label_logit[row];
    // label column is colmask'd in the GEMM; re-add its exp term here
    float Ls = fexp2((lab - CMAX) * LOG2E);
    const float4* pr = (const float4*)(partials + (size_t)row * NSTRIP);
    for (int t = 0; t < NSTRIP / 4; t++) {
        float4 v = pr[t];
        Ls += v.x + v.y + v.z + v.w;
    }
    const float lse = CMAX + logf(Ls);
    const float valid = (log_mask[row] != 0.0f) ? 1.0f : 0.0f;
    float a = (lse - lab) * valid;
    float c = valid;
    __shared__ float sa[4], sc_[4];
    #pragma unroll
    for (int off = 32; off > 0; off >>= 1) {
        a += __shfl_down(a, off, 64);
        c += __shfl_down(c, off, 64);
    }
    const int lane = threadIdx.x & 63, w = threadIdx.x >> 6;
    if (lane == 0) { sa[w] = a; sc_[w] = c; }
    __syncthreads();
    if (threadIdx.x == 0) {
        bsums[blockIdx.x * 2 + 0] = sa[0] + sa[1] + sa[2] + sa[3];
        bsums[blockIdx.x * 2 + 1] = sc_[0] + sc_[1] + sc_[2] + sc_[3];
    }
}

__global__ __launch_bounds__(64) void finalize_kernel(
    const float* __restrict__ bsums, float* __restrict__ out) {
    const int t = threadIdx.x;
    float a = 0.f, c = 0.f;
    if (t < 32) { a = bsums[2 * t]; c = bsums[2 * t + 1]; }
    #pragma unroll
    for (int off = 32; off > 0; off >>= 1) {
        a += __shfl_down(a, off, 64);
        c += __shfl_down(c, off, 64);
    }
    if (t == 0) out[0] = a / c;
}

// ---------------------------------------------------------------- launch
extern "C" void kernel_launch(void* const* d_in, const int* in_sizes, int n_in,
                              void* d_out, int out_size, void* d_ws, size_t ws_size,
                              hipStream_t stream) {
    const int*   ids    = (const int*)d_in[0];
    const float* lm     = (const float*)d_in[1];
    const float* emb    = (const float*)d_in[2];
    const float* pos    = (const float*)d_in[3];
    const float* qkv_w  = (const float*)d_in[4];
    const float* out_w  = (const float*)d_in[5];
    const float* ffn1_w = (const float*)d_in[6];
    const float* ffn2_w = (const float*)d_in[7];
    const float* pop    = (const float*)d_in[8];
    float* out = (float*)d_out;

    char* p = (char*)d_ws;
    auto alloc = [&](size_t bytes) {
        char* r = p;
        p += (bytes + 255) & ~(size_t)255;
        return r;
    };
    typedef __hip_bfloat16 bf16;
    bf16*    sebf     = (bf16*)alloc((size_t)NCOLP * DIM * 2);       // 8.65 MB (padded)
    float*   debias   = (float*)alloc((size_t)NCOLP * 4);
    float*   deb2     = (float*)alloc((size_t)NCOLP * 4);
    uint8_t* padcol   = (uint8_t*)alloc(NCOLP);
    uint8_t* colmask  = (uint8_t*)alloc((size_t)BSZ * NCOLP);        // 1.08 MB (padded)
    bf16*    xb       = (bf16*)alloc((size_t)NROW * DIM * 2);        // 8.4 MB (residual)
    bf16*    xbs      = (bf16*)alloc((size_t)NROW * DIM * 2);        // 8.4 MB (scaled A)
    bf16*    big      = (bf16*)alloc((size_t)NROW * 2048 * 2);       // 33.6 MB (qkv / h)
    bf16*    tmp1     = (bf16*)alloc((size_t)NROW * DIM * 2);        // attn out
    bf16*    tmp2     = (bf16*)alloc((size_t)NROW * DIM * 2);        // proj / f2
    float*   partials = (float*)alloc((size_t)NROW * NSTRIP * 4);    // 4.3 MB
    float*   lab      = (float*)alloc((size_t)NROW * 4);
    float*   bsums    = (float*)alloc(64 * 4);
    bf16*    qkvT     = (bf16*)alloc((size_t)NLAYER * 1536 * 512 * 2);
    bf16*    outT     = (bf16*)alloc((size_t)NLAYER * 512 * 512 * 2);
    bf16*    f1T      = (bf16*)alloc((size_t)NLAYER * 2048 * 512 * 2);
    bf16*    f2T      = (bf16*)alloc((size_t)NLAYER * 512 * 2048 * 2);

    transpose_bf16_kernel<<<dim3(1536 / 32, 512 / 32, NLAYER), 256, 0, stream>>>(
        qkv_w, qkvT, 512, 1536);
    transpose_bf16_kernel<<<dim3(512 / 32, 512 / 32, NLAYER), 256, 0, stream>>>(
        out_w, outT, 512, 512);
    transpose_bf16_kernel<<<dim3(2048 / 32, 512 / 32, NLAYER), 256, 0, stream>>>(
        ffn1_w, f1T, 512, 2048);
    transpose_bf16_kernel<<<dim3(512 / 32, 2048 / 32, NLAYER), 256, 0, stream>>>(
        ffn2_w, f2T, 2048, 512);

    gather_posln_kernel<<<NCOL / 4, 256, 0, stream>>>(ids, emb, pop, pos, sebf, debias, deb2, xb);
    mask_kernel<<<BSZ * 8, 256, 0, stream>>>(ids, lm, colmask, padcol);

    for (int l = 0; l < NLAYER; l++) {
        gemm_bt2_kernel<128, false><<<(1536 / 128) * 64, 256, 0, stream>>>(
            xb, qkvT + (size_t)l * 1536 * 512, big, 1536, 512);
        attn_mfma_kernel<<<BSZ * HEADS, 256, 0, stream>>>(big, lm, tmp1);
        gemm_bt2_kernel<64, false><<<(512 / 64) * 64, 256, 0, stream>>>(
            tmp1, outT + (size_t)l * 512 * 512, tmp2, 512, 512);
        resid_ln_kernel<false><<<NROW / 4, 256, 0, stream>>>(xb, tmp2, nullptr);
        gemm_bt2_kernel<128, true><<<(2048 / 128) * 64, 256, 0, stream>>>(
            xb, f1T + (size_t)l * 2048 * 512, big, 2048, 512);
        gemm_bt2_kernel<64, false><<<(512 / 64) * 64, 256, 0, stream>>>(
            big, f2T + (size_t)l * 512 * 2048, tmp2, 512, 2048);
        if (l == NLAYER - 1)
            resid_ln_kernel<true><<<NROW / 4, 256, 0, stream>>>(xb, tmp2, xbs);
        else
            resid_ln_kernel<false><<<NROW / 4, 256, 0, stream>>>(xb, tmp2, nullptr);
    }

    label_kernel<<<NROW / 4, 256, 0, stream>>>(xb, sebf, debias, padcol, lab);
    gemm256_logits_kernel<<<32 * (NCOLP / 256), 512, 0, stream>>>(
        xbs, sebf, NCOLP, 512, deb2, colmask, partials);
    combine_kernel<<<NROW / 256, 256, 0, stream>>>(partials, lab, lm, bsums);
    finalize_kernel<<<1, 64, 0, stream>>>(bsums, out);
}